// Round 8
// baseline (764.657 us; speedup 1.0000x reference)
//
#include <hip/hip_runtime.h>

// GCN on 1M nodes / 16M edges, collapsed to scalar per-node features.
//
//   deg[c]  = sum_{e: col=c} ew[e] + 1 (self loop)
//   dis     = rsqrt(deg)
//   S1[c]   = dis[c] * (sum_e dis[row]*ew*x[row]) + dis[c]^2 * x[c]
//   g[c]    = sum_j relu(S1[c]*W1[j] + b1[j]) * W2[j]
//   S2[c]   = dis[c] * (sum_e dis[row]*ew*g[row]) + dis[c]^2 * g[c]
//   y[c]    = sigmoid((S2[c]+b2)*Wl + bl)
//
// R7 post-mortem: k_acc pinned at ~117us across 4 geometries with VALU 4%,
// HBM 10%, 0 LDS conflicts -> bound by per-CU L1 miss transactions for 16M
// random 2B gathers (p16 2MB >> L1 32KB; ~64 MSHRs x ~200cyc L2 latency
// ~= 4 cyc/address ~= 117us). Fix = locality: second radix pass sorts each
// col-bucket's records by row>>9 (wave hits ~27 unique lines instead of 64),
// and the sort's histogram pass absorbs the degree accumulation (acc0 gone).

constexpr int N_NODES = 1000000;
constexpr int N_EDGES = 16000000;

constexpr int BSHIFT = 12;
constexpr int BNODES = 1 << BSHIFT;                    // 4096 nodes/bucket
constexpr int NB = (N_NODES + BNODES - 1) / BNODES;    // 245 buckets
constexpr int EPT = 12;                                // edges/thread in count+fill
constexpr int FBLK = 256;
constexpr int CHUNK = FBLK * EPT;                      // 3072 edges/block
constexpr int NBLK = (N_EDGES + CHUNK - 1) / CHUNK;    // 5209
constexpr int NHIST = NB * NBLK;                       // 1,276,205
constexpr int SCAN_TPB = 256;
constexpr int SCAN_EPB = 1024;
constexpr int NSCAN = (NHIST + SCAN_EPB - 1) / SCAN_EPB;  // 1247
constexpr int NHIST_PAD = NSCAN * SCAN_EPB;            // 1,276,928

constexpr int SBS = 9;                                 // secondary key row>>9
constexpr int SBINS = 1 << (20 - SBS);                 // 2048 bins (row < 2^20)
constexpr int SPARTS = 4;                              // parts per bucket

__device__ inline unsigned short f2bf(float f) {   // fp32 -> bf16 RNE
  unsigned u = __float_as_uint(f);
  return (unsigned short)((u + 0x7FFFu + ((u >> 16) & 1u)) >> 16);
}
__device__ inline float bf2f(unsigned short h) {
  return __uint_as_float((unsigned)h << 16);
}

// ---------------- build: count / transpose / scan / transpose / fill --------

// histT layout [NBLK][256]: block writes its own contiguous row (coalesced).
__global__ __launch_bounds__(FBLK) void k_count(const int* __restrict__ col,
                                                unsigned* __restrict__ histT) {
  __shared__ unsigned cnt[256];
  int t = threadIdx.x;
  cnt[t] = 0;
  __syncthreads();
  int e0 = blockIdx.x * CHUNK;
#pragma unroll
  for (int k = 0; k < EPT; ++k) {
    int e = e0 + k * FBLK + t;
    if (e < N_EDGES) atomicAdd(&cnt[col[e] >> BSHIFT], 1u);
  }
  __syncthreads();
  histT[(size_t)blockIdx.x * 256 + t] = cnt[t];
}

// histT[NBLK][256] -> hist[b*NBLK + blk] (bucket-major flat, for linear scan)
__global__ __launch_bounds__(1024) void k_t1(const unsigned* __restrict__ in,
                                             unsigned* __restrict__ out) {
  __shared__ unsigned tile[32][33];
  int bx = blockIdx.x * 32;   // blk base
  int by = blockIdx.y * 32;   // b base
  int tx = threadIdx.x, ty = threadIdx.y;
  int rblk = bx + ty;
  if (rblk < NBLK) tile[ty][tx] = in[(size_t)rblk * 256 + by + tx];
  __syncthreads();
  int wb = by + ty, wblk = bx + tx;
  if (wb < NB && wblk < NBLK) out[(size_t)wb * NBLK + wblk] = tile[tx][ty];
}

// hist offsets (bucket-major) -> histT2[blk*256 + b] (fill reads coalesced)
__global__ __launch_bounds__(1024) void k_t2(const unsigned* __restrict__ in,
                                             unsigned* __restrict__ out) {
  __shared__ unsigned tile[32][33];
  int bx = blockIdx.x * 32;   // blk base
  int by = blockIdx.y * 32;   // b base
  int tx = threadIdx.x, ty = threadIdx.y;
  int rb = by + ty, rblk = bx + tx;
  if (rb < NB && rblk < NBLK) tile[ty][tx] = in[(size_t)rb * NBLK + rblk];
  __syncthreads();
  int wblk = bx + ty, wb = by + tx;
  if (wblk < NBLK && wb < NB) out[(size_t)wblk * 256 + wb] = tile[tx][ty];
}

__global__ __launch_bounds__(SCAN_TPB) void k_scanA(unsigned* __restrict__ h,
                                                    unsigned* __restrict__ bsum) {
  __shared__ unsigned sc[SCAN_TPB];
  int t = threadIdx.x;
  size_t base = (size_t)blockIdx.x * SCAN_EPB + (size_t)t * 4;
  uint4 v = *(const uint4*)(h + base);
  unsigned s = v.x + v.y + v.z + v.w;
  sc[t] = s;
  __syncthreads();
  for (int d = 1; d < SCAN_TPB; d <<= 1) {
    unsigned u = (t >= d) ? sc[t - d] : 0;
    __syncthreads();
    sc[t] += u;
    __syncthreads();
  }
  unsigned ex = sc[t] - s;
  uint4 o;
  o.x = ex; o.y = ex + v.x; o.z = ex + v.x + v.y; o.w = ex + v.x + v.y + v.z;
  *(uint4*)(h + base) = o;
  if (t == SCAN_TPB - 1) bsum[blockIdx.x] = sc[t];
}

__global__ __launch_bounds__(1024) void k_scanB(unsigned* __restrict__ bsum) {
  __shared__ unsigned sc[1024];
  int t = threadIdx.x;
  unsigned a0 = (2 * t < NSCAN) ? bsum[2 * t] : 0;
  unsigned a1 = (2 * t + 1 < NSCAN) ? bsum[2 * t + 1] : 0;
  unsigned s = a0 + a1;
  sc[t] = s;
  __syncthreads();
  for (int d = 1; d < 1024; d <<= 1) {
    unsigned u = (t >= d) ? sc[t - d] : 0;
    __syncthreads();
    sc[t] += u;
    __syncthreads();
  }
  unsigned ex = sc[t] - s;
  if (2 * t < NSCAN) bsum[2 * t] = ex;
  if (2 * t + 1 < NSCAN) bsum[2 * t + 1] = ex + a0;
}

__global__ __launch_bounds__(SCAN_TPB) void k_scanC(unsigned* __restrict__ h,
                                                    const unsigned* __restrict__ bsum) {
  unsigned add = bsum[blockIdx.x];
  size_t base = (size_t)blockIdx.x * SCAN_EPB + (size_t)threadIdx.x * 4;
  uint4 v = *(uint4*)(h + base);
  v.x += add; v.y += add; v.z += add; v.w += add;
  *(uint4*)(h + base) = v;
}

// Register-stash + LDS-reorder fill: coalesced plain record writes.
// record = (row<<12 | col&0xFFF, bits(ew)); row < 2^20 fits.
__global__ __launch_bounds__(FBLK) void k_fill(const int* __restrict__ row,
                                               const int* __restrict__ col,
                                               const float* __restrict__ ew,
                                               const unsigned* __restrict__ histT2,
                                               uint2* __restrict__ rec) {
  __shared__ unsigned lhist[256];
  __shared__ unsigned lb[256];
  __shared__ unsigned tail[256];
  __shared__ unsigned gbase[NB];
  __shared__ uint2 stage[CHUNK];
  __shared__ unsigned char sbkt[CHUNK];

  int t = threadIdx.x;
  int blk = blockIdx.x;
  lhist[t] = 0;
  for (int i = t; i < NB; i += FBLK)
    gbase[i] = histT2[(size_t)blk * 256 + i];          // coalesced row read
  __syncthreads();

  int e0 = blk * CHUNK;
  unsigned pk[EPT], wv[EPT];
  int bk[EPT];
#pragma unroll
  for (int k = 0; k < EPT; ++k) {
    int e = e0 + k * FBLK + t;
    bk[k] = -1;
    if (e < N_EDGES) {
      int c = col[e];
      pk[k] = ((unsigned)row[e] << BSHIFT) | (unsigned)(c & (BNODES - 1));
      wv[k] = __float_as_uint(ew[e]);
      bk[k] = c >> BSHIFT;
      atomicAdd(&lhist[bk[k]], 1u);
    }
  }
  __syncthreads();

  unsigned own = lhist[t];
  lb[t] = own;
  __syncthreads();
  for (int d = 1; d < 256; d <<= 1) {   // Hillis-Steele inclusive
    unsigned u = (t >= d) ? lb[t - d] : 0;
    __syncthreads();
    lb[t] += u;
    __syncthreads();
  }
  unsigned total = lb[255];
  unsigned ex = lb[t] - own;
  __syncthreads();
  lb[t] = ex;
  tail[t] = ex;
  __syncthreads();

#pragma unroll
  for (int k = 0; k < EPT; ++k) {
    if (bk[k] >= 0) {
      unsigned s = atomicAdd(&tail[bk[k]], 1u);
      stage[s] = make_uint2(pk[k], wv[k]);
      sbkt[s] = (unsigned char)bk[k];
    }
  }
  __syncthreads();

  for (unsigned s = t; s < total; s += FBLK) {
    unsigned b = sbkt[s];
    rec[gbase[b] + (s - lb[b])] = stage[s];
  }
}

// ---------------- secondary sort (by row>>9 within col-bucket) + deg --------

// Per-(bucket,part): local SBINS histogram -> h2; per-bucket deg partial -> D.
__global__ __launch_bounds__(1024) void k_s2hist(const uint2* __restrict__ rec,
                                                 const unsigned* __restrict__ hist,
                                                 unsigned* __restrict__ h2,
                                                 float* __restrict__ D) {
  __shared__ unsigned rh[SBINS];     // 8KB
  __shared__ float dacc[BNODES];     // 16KB
  int t = threadIdx.x;
  for (int j = t; j < SBINS; j += 1024) rh[j] = 0;
  for (int j = t; j < BNODES; j += 1024) dacc[j] = 0.f;
  __syncthreads();
  int b = blockIdx.x / SPARTS, p = blockIdx.x % SPARTS;
  unsigned bs = hist[(size_t)b * NBLK];
  unsigned be = (b + 1 < NB) ? hist[(size_t)(b + 1) * NBLK] : (unsigned)N_EDGES;
  unsigned len = be - bs;
  unsigned s = bs + (unsigned)(((unsigned long long)len * p) / SPARTS);
  unsigned e = bs + (unsigned)(((unsigned long long)len * (p + 1)) / SPARTS);
  for (unsigned i = s + t; i < e; i += 1024u) {
    unsigned long long r = __builtin_nontemporal_load(
        (const unsigned long long*)&rec[i]);
    unsigned pk = (unsigned)r;
    atomicAdd(&rh[pk >> (BSHIFT + SBS)], 1u);   // bin = row>>9 = pk>>21
    atomicAdd(&dacc[pk & (BNODES - 1)], __uint_as_float((unsigned)(r >> 32)));
  }
  __syncthreads();
  unsigned* hrow = h2 + (size_t)blockIdx.x * SBINS;
  for (int j = t; j < SBINS; j += 1024) hrow[j] = rh[j];
  float* o = D + (size_t)p * N_NODES;
  int base = b * BNODES;
  for (int j = t; j < BNODES && base + j < N_NODES; j += 1024)
    o[base + j] = dacc[j];
}

// Per-(bucket,part): compute per-bin write offsets from h2, scatter rec->rec2.
// Ordering within bucket: bin-major, then part, then arrival.
__global__ __launch_bounds__(1024) void k_s2place(const uint2* __restrict__ rec,
                                                  const unsigned* __restrict__ hist,
                                                  const unsigned* __restrict__ h2,
                                                  unsigned long long* __restrict__ rec2) {
  __shared__ unsigned offs[SBINS];   // pre-part offset, then running tails
  __shared__ unsigned tsum[SBINS];   // per-bin total across parts
  __shared__ unsigned sc[1024];
  int t = threadIdx.x;
  int b = blockIdx.x / SPARTS, p = blockIdx.x % SPARTS;
  unsigned bs = hist[(size_t)b * NBLK];
  unsigned be = (b + 1 < NB) ? hist[(size_t)(b + 1) * NBLK] : (unsigned)N_EDGES;
  unsigned len = be - bs;
  unsigned s = bs + (unsigned)(((unsigned long long)len * p) / SPARTS);
  unsigned e = bs + (unsigned)(((unsigned long long)len * (p + 1)) / SPARTS);

  for (int j = t; j < SBINS; j += 1024) {
    unsigned pre = 0, tot = 0;
    for (int q = 0; q < SPARTS; ++q) {
      unsigned v = h2[(size_t)(b * SPARTS + q) * SBINS + j];
      tot += v;
      if (q < p) pre += v;
    }
    offs[j] = pre;
    tsum[j] = tot;
  }
  __syncthreads();
  // exclusive scan of tsum over SBINS (2 bins/thread)
  int j0 = t * 2;
  unsigned l0 = tsum[j0], l1 = tsum[j0 + 1];
  unsigned lsum = l0 + l1;
  sc[t] = lsum;
  __syncthreads();
  for (int d = 1; d < 1024; d <<= 1) {
    unsigned u = (t >= d) ? sc[t - d] : 0;
    __syncthreads();
    sc[t] += u;
    __syncthreads();
  }
  unsigned ex = sc[t] - lsum;
  offs[j0]     = bs + ex + offs[j0];
  offs[j0 + 1] = bs + ex + l0 + offs[j0 + 1];
  __syncthreads();

  for (unsigned i = s + t; i < e; i += 1024u) {
    unsigned long long r = __builtin_nontemporal_load(
        (const unsigned long long*)&rec[i]);
    unsigned bin = ((unsigned)r) >> (BSHIFT + SBS);
    unsigned dest = atomicAdd(&offs[bin], 1u);
    rec2[dest] = r;    // plain store (L2 write-combining; nt stores cost +45us)
  }
}

// ---------------- accumulate: one (bucket,part) per block ----------------
// mode 0: val = ew (weighted degree, fallback path only).
// mode 1: val = ew * bf16 p16[row].
__global__ __launch_bounds__(512) void k_acc(const uint2* __restrict__ rec,
                                             const unsigned* __restrict__ hist,
                                             const unsigned short* __restrict__ p16,
                                             float* __restrict__ out,
                                             int mode, int split) {
  __shared__ float acc[BNODES];
  for (int i = threadIdx.x; i < BNODES; i += 512) acc[i] = 0.f;
  __syncthreads();
  int b = blockIdx.x / split;
  int part = blockIdx.x - b * split;
  unsigned bs = hist[(size_t)b * NBLK];
  unsigned be = (b + 1 < NB) ? hist[(size_t)(b + 1) * NBLK] : (unsigned)N_EDGES;
  unsigned len = be - bs;
  unsigned s = bs + (unsigned)(((unsigned long long)len * part) / split);
  unsigned e = bs + (unsigned)(((unsigned long long)len * (part + 1)) / split);

  unsigned i = s + threadIdx.x;
  for (; i + 7u * 512u < e; i += 8u * 512u) {   // 8 records in flight
    unsigned long long r[8];
#pragma unroll
    for (int j = 0; j < 8; ++j)
      r[j] = __builtin_nontemporal_load(
          (const unsigned long long*)&rec[i + (unsigned)j * 512u]);
    float v[8];
#pragma unroll
    for (int j = 0; j < 8; ++j) {
      v[j] = __uint_as_float((unsigned)(r[j] >> 32));
      if (mode) v[j] *= bf2f(p16[(unsigned)r[j] >> BSHIFT]);
    }
#pragma unroll
    for (int j = 0; j < 8; ++j)
      atomicAdd(&acc[(unsigned)r[j] & (BNODES - 1)], v[j]);
  }
  for (; i < e; i += 512u) {
    unsigned long long r = __builtin_nontemporal_load(
        (const unsigned long long*)&rec[i]);
    float v = __uint_as_float((unsigned)(r >> 32));
    if (mode) v *= bf2f(p16[(unsigned)r >> BSHIFT]);
    atomicAdd(&acc[(unsigned)r & (BNODES - 1)], v);
  }
  __syncthreads();

  float* o = out + (size_t)part * N_NODES;
  int base = b * BNODES;
  for (int j = threadIdx.x; j < BNODES && base + j < N_NODES; j += 512)
    o[base + j] = acc[j];
}

// ---------------- node-wise kernels ----------------

__global__ void k_dis_p(const float* __restrict__ x, const float* __restrict__ D,
                        float* __restrict__ A, unsigned short* __restrict__ P16,
                        int split) {
  int i = blockIdx.x * blockDim.x + threadIdx.x;
  if (i >= N_NODES) return;
  float deg = 1.0f;                       // self loop
  for (int j = 0; j < split; ++j) deg += D[(size_t)j * N_NODES + i];
  float d = rsqrtf(deg);
  A[i] = d;
  P16[i] = f2bf(d * x[i]);
}

__global__ void k_g2(const float* __restrict__ A, const float* __restrict__ x,
                     const float* __restrict__ D, unsigned short* __restrict__ P16,
                     const float* __restrict__ W1, const float* __restrict__ b1,
                     const float* __restrict__ W2, int split) {
  int i = blockIdx.x * blockDim.x + threadIdx.x;
  if (i >= N_NODES) return;
  float d = A[i];
  float sraw = 0.f;
  for (int j = 0; j < split; ++j) sraw += D[(size_t)j * N_NODES + i];
  float s1 = d * sraw + d * d * x[i];
  float g = 0.f;
#pragma unroll
  for (int j = 0; j < 4; ++j) {
    float h = fmaf(s1, W1[j], b1[j]);
    g = fmaf(fmaxf(h, 0.f), W2[j], g);
  }
  P16[i] = f2bf(d * g);
}

__global__ void k_out2(const float* __restrict__ A,
                       const unsigned short* __restrict__ P16,
                       const float* __restrict__ D, const float* __restrict__ b2,
                       const float* __restrict__ Wl, const float* __restrict__ bl,
                       float* __restrict__ y, int split) {
  int i = blockIdx.x * blockDim.x + threadIdx.x;
  if (i >= N_NODES) return;
  float d = A[i];
  float g = bf2f(P16[i]) / d;             // d in (0,1], safe
  float sraw = 0.f;
  for (int j = 0; j < split; ++j) sraw += D[(size_t)j * N_NODES + i];
  float agg2 = d * sraw + d * d * g;
  float v = fmaf(agg2 + b2[0], Wl[0], bl[0]);
  y[i] = 1.0f / (1.0f + expf(-v));
}

// ---------------- fallback (round-2 global-atomic path) ----------------

__global__ void f_deg(const int* __restrict__ col, const float* __restrict__ ew,
                      float* __restrict__ deg) {
  int i = blockIdx.x * blockDim.x + threadIdx.x;
  int stride = gridDim.x * blockDim.x;
  for (int e = i; e < N_EDGES; e += stride) atomicAdd(&deg[col[e]], ew[e]);
}
__global__ void f_dis(float* __restrict__ a) {
  int i = blockIdx.x * blockDim.x + threadIdx.x;
  if (i < N_NODES) a[i] = rsqrtf(a[i] + 1.0f);
}
__global__ void f_scatter(const int* __restrict__ row, const int* __restrict__ col,
                          const float* __restrict__ ew, const float* __restrict__ dis,
                          const float* __restrict__ src, float* __restrict__ acc) {
  int i = blockIdx.x * blockDim.x + threadIdx.x;
  int stride = gridDim.x * blockDim.x;
  for (int e = i; e < N_EDGES; e += stride) {
    int r = row[e]; int c = col[e];
    atomicAdd(&acc[c], dis[r] * ew[e] * src[r]);
  }
}
__global__ void f_g(const float* __restrict__ dis, const float* __restrict__ x,
                    float* __restrict__ s1g, const float* __restrict__ W1,
                    const float* __restrict__ b1, const float* __restrict__ W2) {
  int i = blockIdx.x * blockDim.x + threadIdx.x;
  if (i >= N_NODES) return;
  float d = dis[i];
  float s1 = d * s1g[i] + d * d * x[i];
  float g = 0.f;
#pragma unroll
  for (int j = 0; j < 4; ++j) {
    float h = fmaf(s1, W1[j], b1[j]);
    g = fmaf(fmaxf(h, 0.f), W2[j], g);
  }
  s1g[i] = g;
}
__global__ void f_out(const float* __restrict__ dis, const float* __restrict__ g,
                      float* __restrict__ s2out, const float* __restrict__ b2,
                      const float* __restrict__ Wl, const float* __restrict__ bl) {
  int i = blockIdx.x * blockDim.x + threadIdx.x;
  if (i >= N_NODES) return;
  float d = dis[i];
  float agg2 = d * s2out[i] + d * d * g[i];
  float v = fmaf(agg2 + b2[0], Wl[0], bl[0]);
  s2out[i] = 1.0f / (1.0f + expf(-v));
}

// ---------------- launch ----------------

extern "C" void kernel_launch(void* const* d_in, const int* in_sizes, int n_in,
                              void* d_out, int out_size, void* d_ws, size_t ws_size,
                              hipStream_t stream) {
  const float* x  = (const float*)d_in[0];
  const int* ei   = (const int*)d_in[1];   // int32 (harness narrows int64)
  const float* ew = (const float*)d_in[2];
  const float* W1 = (const float*)d_in[3];
  const float* b1 = (const float*)d_in[4];
  const float* W2 = (const float*)d_in[5];
  const float* b2 = (const float*)d_in[6];
  const float* Wl = (const float*)d_in[7];
  const float* bl = (const float*)d_in[8];

  const int* row = ei;
  const int* col = ei + N_EDGES;

  auto pad = [](size_t v) { return (v + 255) & ~(size_t)255; };
  const size_t REC_B   = pad((size_t)N_EDGES * 8);         // 128,000,000
  const size_t HIST_B  = pad((size_t)NHIST_PAD * 4);       // 5,107,712
  const size_t HISTT_B = pad((size_t)NBLK * 256 * 4);      // 5,334,016
  const size_t BSUM_B  = 8192;
  const size_t H2_B    = pad((size_t)NB * SPARTS * SBINS * 4);  // ~8MB
  const size_t NODE_B  = pad((size_t)N_NODES * 4);
  const size_t P16_B   = pad((size_t)N_NODES * 2);
  const size_t BASE    = REC_B + HIST_B + HISTT_B + BSUM_B + NODE_B + P16_B;
  const size_t REQ_SORT = BASE + REC_B + H2_B + (size_t)SPARTS * NODE_B;
  // R7-path requirement (no rec2/h2, split s partials):
  auto req_r7 = [&](int s) { return BASE + (size_t)s * NODE_B; };

  dim3 blk(256);
  dim3 ngrid((N_NODES + 255) / 256);
  dim3 tgrid((NBLK + 31) / 32, 8);
  dim3 tblk(32, 32);

  if (ws_size >= REQ_SORT) {
    char* w = (char*)d_ws;
    uint2* rec          = (uint2*)w;
    unsigned long long* rec2 = (unsigned long long*)(w + REC_B);
    unsigned* hist      = (unsigned*)(w + 2 * REC_B);
    unsigned* histT     = (unsigned*)(w + 2 * REC_B + HIST_B);
    unsigned* bsum      = (unsigned*)(w + 2 * REC_B + HIST_B + HISTT_B);
    unsigned* h2        = (unsigned*)(w + 2 * REC_B + HIST_B + HISTT_B + BSUM_B);
    float* A            = (float*)((char*)h2 + H2_B);
    unsigned short* P16 = (unsigned short*)((char*)A + NODE_B);
    float* D            = (float*)((char*)P16 + P16_B);   // SPARTS partials

    hipMemsetAsync(hist + NHIST, 0, (size_t)(NHIST_PAD - NHIST) * 4, stream);

    k_count <<<NBLK, FBLK, 0, stream>>>(col, histT);
    k_t1    <<<tgrid, tblk, 0, stream>>>(histT, hist);
    k_scanA <<<NSCAN, SCAN_TPB, 0, stream>>>(hist, bsum);
    k_scanB <<<1, 1024, 0, stream>>>(bsum);
    k_scanC <<<NSCAN, SCAN_TPB, 0, stream>>>(hist, bsum);
    k_t2    <<<tgrid, tblk, 0, stream>>>(hist, histT);
    k_fill  <<<NBLK, FBLK, 0, stream>>>(row, col, ew, histT, rec);

    k_s2hist <<<NB * SPARTS, 1024, 0, stream>>>(rec, hist, h2, D);  // + deg
    k_dis_p  <<<ngrid, blk, 0, stream>>>(x, D, A, P16, SPARTS);
    k_s2place<<<NB * SPARTS, 1024, 0, stream>>>(rec, hist, h2, rec2);

    k_acc  <<<NB * 4, 512, 0, stream>>>((const uint2*)rec2, hist, P16, D, 1, 4);
    k_g2   <<<ngrid, blk, 0, stream>>>(A, x, D, P16, W1, b1, W2, 4);
    k_acc  <<<NB * 4, 512, 0, stream>>>((const uint2*)rec2, hist, P16, D, 1, 4);
    k_out2 <<<ngrid, blk, 0, stream>>>(A, P16, D, b2, Wl, bl, (float*)d_out, 4);
  } else {
    int split = 0;
    for (int s : {4, 2, 1})
      if (ws_size >= req_r7(s)) { split = s; break; }
    if (split) {
      char* w = (char*)d_ws;
      uint2* rec          = (uint2*)w;
      unsigned* hist      = (unsigned*)(w + REC_B);
      unsigned* histT     = (unsigned*)(w + REC_B + HIST_B);
      unsigned* bsum      = (unsigned*)(w + REC_B + HIST_B + HISTT_B);
      float* A            = (float*)(w + REC_B + HIST_B + HISTT_B + BSUM_B);
      unsigned short* P16 = (unsigned short*)((char*)A + NODE_B);
      float* D            = (float*)((char*)P16 + P16_B);

      hipMemsetAsync(hist + NHIST, 0, (size_t)(NHIST_PAD - NHIST) * 4, stream);
      k_count<<<NBLK, FBLK, 0, stream>>>(col, histT);
      k_t1   <<<tgrid, tblk, 0, stream>>>(histT, hist);
      k_scanA<<<NSCAN, SCAN_TPB, 0, stream>>>(hist, bsum);
      k_scanB<<<1, 1024, 0, stream>>>(bsum);
      k_scanC<<<NSCAN, SCAN_TPB, 0, stream>>>(hist, bsum);
      k_t2   <<<tgrid, tblk, 0, stream>>>(hist, histT);
      k_fill <<<NBLK, FBLK, 0, stream>>>(row, col, ew, histT, rec);

      k_acc  <<<NB * split, 512, 0, stream>>>(rec, hist, nullptr, D, 0, split);
      k_dis_p<<<ngrid, blk, 0, stream>>>(x, D, A, P16, split);
      k_acc  <<<NB * split, 512, 0, stream>>>(rec, hist, P16, D, 1, split);
      k_g2   <<<ngrid, blk, 0, stream>>>(A, x, D, P16, W1, b1, W2, split);
      k_acc  <<<NB * split, 512, 0, stream>>>(rec, hist, P16, D, 1, split);
      k_out2 <<<ngrid, blk, 0, stream>>>(A, P16, D, b2, Wl, bl, (float*)d_out, split);
    } else {
      float* Aw = (float*)d_ws;
      float* Bw = Aw + N_NODES;
      float* Cw = (float*)d_out;
      hipMemsetAsync(d_ws, 0, 2ull * N_NODES * 4, stream);
      hipMemsetAsync(d_out, 0, (size_t)N_NODES * 4, stream);
      dim3 egrid(4096);
      f_deg<<<egrid, blk, 0, stream>>>(col, ew, Aw);
      f_dis<<<ngrid, blk, 0, stream>>>(Aw);
      f_scatter<<<egrid, blk, 0, stream>>>(row, col, ew, Aw, x, Bw);
      f_g<<<ngrid, blk, 0, stream>>>(Aw, x, Bw, W1, b1, W2);
      f_scatter<<<egrid, blk, 0, stream>>>(row, col, ew, Aw, Bw, Cw);
      f_out<<<ngrid, blk, 0, stream>>>(Aw, Bw, Cw, b2, Wl, bl);
    }
  }
}

// Round 9
// 459.555 us; speedup vs baseline: 1.6639x; 1.6639x over previous
//
#include <hip/hip_runtime.h>

// GCN on 1M nodes / 16M edges, collapsed to scalar per-node features.
//
//   deg[c]  = sum_{e: col=c} ew[e] + 1 (self loop)
//   dis     = rsqrt(deg)
//   S1[c]   = dis[c] * (sum_e dis[row]*ew*x[row]) + dis[c]^2 * x[c]
//   g[c]    = sum_j relu(S1[c]*W1[j] + b1[j]) * W2[j]
//   S2[c]   = dis[c] * (sum_e dis[row]*ew*g[row]) + dis[c]^2 * g[c]
//   y[c]    = sigmoid((S2[c]+b2)*Wl + bl)
//
// R8 post-mortem: secondary sort's place pass wrote 447MB for a 128MB
// permutation (sub-line runs, same pathology as R3) -> cost 310us > the
// ~120us of gather-locality savings. Reverted.
// R9 = R7 + (a) k_fill wave-shuffle scan (5 barriers vs 19) + unguarded
// fast-path loads + unrolled writeout; (b) k_acc 256thr x split8 = 8
// blocks/CU, 32 waves/CU -- tests MSHR-bound vs wave-bound for the gather.

constexpr int N_NODES = 1000000;
constexpr int N_EDGES = 16000000;

constexpr int BSHIFT = 12;
constexpr int BNODES = 1 << BSHIFT;                    // 4096 nodes/bucket
constexpr int NB = (N_NODES + BNODES - 1) / BNODES;    // 245 buckets
constexpr int EPT = 12;                                // edges/thread in count+fill
constexpr int FBLK = 256;
constexpr int CHUNK = FBLK * EPT;                      // 3072 edges/block
constexpr int NBLK = (N_EDGES + CHUNK - 1) / CHUNK;    // 5209
constexpr int NHIST = NB * NBLK;                       // 1,276,205
constexpr int SCAN_TPB = 256;
constexpr int SCAN_EPB = 1024;
constexpr int NSCAN = (NHIST + SCAN_EPB - 1) / SCAN_EPB;  // 1247
constexpr int NHIST_PAD = NSCAN * SCAN_EPB;            // 1,276,928

__device__ inline unsigned short f2bf(float f) {   // fp32 -> bf16 RNE
  unsigned u = __float_as_uint(f);
  return (unsigned short)((u + 0x7FFFu + ((u >> 16) & 1u)) >> 16);
}
__device__ inline float bf2f(unsigned short h) {
  return __uint_as_float((unsigned)h << 16);
}

// ---------------- build: count / transpose / scan / transpose / fill --------

// histT layout [NBLK][256]: block writes its own contiguous row (coalesced).
__global__ __launch_bounds__(FBLK) void k_count(const int* __restrict__ col,
                                                unsigned* __restrict__ histT) {
  __shared__ unsigned cnt[256];
  int t = threadIdx.x;
  cnt[t] = 0;
  __syncthreads();
  int e0 = blockIdx.x * CHUNK;
  if (e0 + CHUNK <= N_EDGES) {          // fast path: all loads unguarded
    int c[EPT];
#pragma unroll
    for (int k = 0; k < EPT; ++k) c[k] = col[e0 + k * FBLK + t];
#pragma unroll
    for (int k = 0; k < EPT; ++k) atomicAdd(&cnt[c[k] >> BSHIFT], 1u);
  } else {
#pragma unroll
    for (int k = 0; k < EPT; ++k) {
      int e = e0 + k * FBLK + t;
      if (e < N_EDGES) atomicAdd(&cnt[col[e] >> BSHIFT], 1u);
    }
  }
  __syncthreads();
  histT[(size_t)blockIdx.x * 256 + t] = cnt[t];
}

// histT[NBLK][256] -> hist[b*NBLK + blk] (bucket-major flat, for linear scan)
__global__ __launch_bounds__(1024) void k_t1(const unsigned* __restrict__ in,
                                             unsigned* __restrict__ out) {
  __shared__ unsigned tile[32][33];
  int bx = blockIdx.x * 32;   // blk base
  int by = blockIdx.y * 32;   // b base
  int tx = threadIdx.x, ty = threadIdx.y;
  int rblk = bx + ty;
  if (rblk < NBLK) tile[ty][tx] = in[(size_t)rblk * 256 + by + tx];
  __syncthreads();
  int wb = by + ty, wblk = bx + tx;
  if (wb < NB && wblk < NBLK) out[(size_t)wb * NBLK + wblk] = tile[tx][ty];
}

// hist offsets (bucket-major) -> histT2[blk*256 + b] (fill reads coalesced)
__global__ __launch_bounds__(1024) void k_t2(const unsigned* __restrict__ in,
                                             unsigned* __restrict__ out) {
  __shared__ unsigned tile[32][33];
  int bx = blockIdx.x * 32;   // blk base
  int by = blockIdx.y * 32;   // b base
  int tx = threadIdx.x, ty = threadIdx.y;
  int rb = by + ty, rblk = bx + tx;
  if (rb < NB && rblk < NBLK) tile[ty][tx] = in[(size_t)rb * NBLK + rblk];
  __syncthreads();
  int wblk = bx + ty, wb = by + tx;
  if (wblk < NBLK && wb < NB) out[(size_t)wblk * 256 + wb] = tile[tx][ty];
}

__global__ __launch_bounds__(SCAN_TPB) void k_scanA(unsigned* __restrict__ h,
                                                    unsigned* __restrict__ bsum) {
  __shared__ unsigned sc[SCAN_TPB];
  int t = threadIdx.x;
  size_t base = (size_t)blockIdx.x * SCAN_EPB + (size_t)t * 4;
  uint4 v = *(const uint4*)(h + base);
  unsigned s = v.x + v.y + v.z + v.w;
  sc[t] = s;
  __syncthreads();
  for (int d = 1; d < SCAN_TPB; d <<= 1) {
    unsigned u = (t >= d) ? sc[t - d] : 0;
    __syncthreads();
    sc[t] += u;
    __syncthreads();
  }
  unsigned ex = sc[t] - s;
  uint4 o;
  o.x = ex; o.y = ex + v.x; o.z = ex + v.x + v.y; o.w = ex + v.x + v.y + v.z;
  *(uint4*)(h + base) = o;
  if (t == SCAN_TPB - 1) bsum[blockIdx.x] = sc[t];
}

__global__ __launch_bounds__(1024) void k_scanB(unsigned* __restrict__ bsum) {
  __shared__ unsigned sc[1024];
  int t = threadIdx.x;
  unsigned a0 = (2 * t < NSCAN) ? bsum[2 * t] : 0;
  unsigned a1 = (2 * t + 1 < NSCAN) ? bsum[2 * t + 1] : 0;
  unsigned s = a0 + a1;
  sc[t] = s;
  __syncthreads();
  for (int d = 1; d < 1024; d <<= 1) {
    unsigned u = (t >= d) ? sc[t - d] : 0;
    __syncthreads();
    sc[t] += u;
    __syncthreads();
  }
  unsigned ex = sc[t] - s;
  if (2 * t < NSCAN) bsum[2 * t] = ex;
  if (2 * t + 1 < NSCAN) bsum[2 * t + 1] = ex + a0;
}

__global__ __launch_bounds__(SCAN_TPB) void k_scanC(unsigned* __restrict__ h,
                                                    const unsigned* __restrict__ bsum) {
  unsigned add = bsum[blockIdx.x];
  size_t base = (size_t)blockIdx.x * SCAN_EPB + (size_t)threadIdx.x * 4;
  uint4 v = *(uint4*)(h + base);
  v.x += add; v.y += add; v.z += add; v.w += add;
  *(uint4*)(h + base) = v;
}

// Register-stash + LDS-reorder fill. Wave-shuffle scan (5 barriers), plain
// coalesced stores (nt stores cost +45us, R5/R6), 4x unrolled writeout.
// record = (row<<12 | col&0xFFF, bits(ew)); row < 2^20 fits.
__global__ __launch_bounds__(FBLK) void k_fill(const int* __restrict__ row,
                                               const int* __restrict__ col,
                                               const float* __restrict__ ew,
                                               const unsigned* __restrict__ histT2,
                                               uint2* __restrict__ rec) {
  __shared__ unsigned lhist[256];
  __shared__ unsigned lb[256];
  __shared__ unsigned tail[256];
  __shared__ unsigned gbase[NB];
  __shared__ unsigned wsum[4];
  __shared__ uint2 stage[CHUNK];
  __shared__ unsigned char sbkt[CHUNK];

  int t = threadIdx.x;
  int blk = blockIdx.x;
  lhist[t] = 0;
  if (t < NB) gbase[t] = histT2[(size_t)blk * 256 + t];  // coalesced row read
  __syncthreads();                                        // B1

  int e0 = blk * CHUNK;
  unsigned pk[EPT], wv[EPT];
  int bk[EPT];
  if (e0 + CHUNK <= N_EDGES) {          // fast path (5208 of 5209 blocks)
#pragma unroll
    for (int k = 0; k < EPT; ++k) {
      int e = e0 + k * FBLK + t;
      int c = col[e];
      pk[k] = ((unsigned)row[e] << BSHIFT) | (unsigned)(c & (BNODES - 1));
      wv[k] = __float_as_uint(ew[e]);
      bk[k] = c >> BSHIFT;
    }
#pragma unroll
    for (int k = 0; k < EPT; ++k) atomicAdd(&lhist[bk[k]], 1u);
  } else {
#pragma unroll
    for (int k = 0; k < EPT; ++k) {
      int e = e0 + k * FBLK + t;
      bk[k] = -1;
      if (e < N_EDGES) {
        int c = col[e];
        pk[k] = ((unsigned)row[e] << BSHIFT) | (unsigned)(c & (BNODES - 1));
        wv[k] = __float_as_uint(ew[e]);
        bk[k] = c >> BSHIFT;
        atomicAdd(&lhist[bk[k]], 1u);
      }
    }
  }
  __syncthreads();                                        // B2

  // exclusive prefix over 256 bucket counts: wave scan + 4-entry fixup
  unsigned own = lhist[t];
  unsigned v = own;
#pragma unroll
  for (int d = 1; d < 64; d <<= 1) {
    unsigned u = __shfl_up(v, d, 64);
    if ((t & 63) >= d) v += u;
  }
  if ((t & 63) == 63) wsum[t >> 6] = v;
  __syncthreads();                                        // B3
  unsigned wbase = 0;
#pragma unroll
  for (int w = 0; w < 4; ++w)
    if (w < (t >> 6)) wbase += wsum[w];
  unsigned total = wsum[0] + wsum[1] + wsum[2] + wsum[3];
  unsigned ex = wbase + v - own;
  lb[t] = ex;
  tail[t] = ex;
  __syncthreads();                                        // B4

  if (e0 + CHUNK <= N_EDGES) {
#pragma unroll
    for (int k = 0; k < EPT; ++k) {
      unsigned s = atomicAdd(&tail[bk[k]], 1u);
      stage[s] = make_uint2(pk[k], wv[k]);
      sbkt[s] = (unsigned char)bk[k];
    }
  } else {
#pragma unroll
    for (int k = 0; k < EPT; ++k) {
      if (bk[k] >= 0) {
        unsigned s = atomicAdd(&tail[bk[k]], 1u);
        stage[s] = make_uint2(pk[k], wv[k]);
        sbkt[s] = (unsigned char)bk[k];
      }
    }
  }
  __syncthreads();                                        // B5

  // staged order is bucket-sorted: consecutive s -> consecutive global dest.
  // 4x unroll: independent LDS-read -> store chains in flight.
  unsigned s = t;
  for (; s + 3u * FBLK < total; s += 4u * FBLK) {
#pragma unroll
    for (int u = 0; u < 4; ++u) {
      unsigned si = s + u * FBLK;
      unsigned b = sbkt[si];
      rec[gbase[b] + (si - lb[b])] = stage[si];
    }
  }
  for (; s < total; s += FBLK) {
    unsigned b = sbkt[s];
    rec[gbase[b] + (s - lb[b])] = stage[s];
  }
}

// ---------------- accumulate: one (bucket,part) per block ----------------
// mode 0: val = ew (weighted degree). mode 1: val = ew * bf16 p16[row].
// 256 threads: split=8 -> 1960 blocks, 8 blocks/CU, 32 waves/CU.
__global__ __launch_bounds__(256) void k_acc(const uint2* __restrict__ rec,
                                             const unsigned* __restrict__ hist,
                                             const unsigned short* __restrict__ p16,
                                             float* __restrict__ out,
                                             int mode, int split) {
  __shared__ float acc[BNODES];
  {
    float4* a4 = (float4*)acc;
#pragma unroll
    for (int i = threadIdx.x; i < BNODES / 4; i += 256)
      a4[i] = make_float4(0.f, 0.f, 0.f, 0.f);
  }
  __syncthreads();
  int b = blockIdx.x / split;
  int part = blockIdx.x - b * split;
  unsigned bs = hist[(size_t)b * NBLK];
  unsigned be = (b + 1 < NB) ? hist[(size_t)(b + 1) * NBLK] : (unsigned)N_EDGES;
  unsigned len = be - bs;
  unsigned s = bs + (unsigned)(((unsigned long long)len * part) / split);
  unsigned e = bs + (unsigned)(((unsigned long long)len * (part + 1)) / split);

  unsigned i = s + threadIdx.x;
  for (; i + 7u * 256u < e; i += 8u * 256u) {   // 8 records in flight
    unsigned long long r[8];
#pragma unroll
    for (int j = 0; j < 8; ++j)
      r[j] = __builtin_nontemporal_load(
          (const unsigned long long*)&rec[i + (unsigned)j * 256u]);
    float v[8];
#pragma unroll
    for (int j = 0; j < 8; ++j) {
      v[j] = __uint_as_float((unsigned)(r[j] >> 32));
      if (mode) v[j] *= bf2f(p16[(unsigned)r[j] >> BSHIFT]);
    }
#pragma unroll
    for (int j = 0; j < 8; ++j)
      atomicAdd(&acc[(unsigned)r[j] & (BNODES - 1)], v[j]);
  }
  for (; i < e; i += 256u) {
    unsigned long long r = __builtin_nontemporal_load(
        (const unsigned long long*)&rec[i]);
    float v = __uint_as_float((unsigned)(r >> 32));
    if (mode) v *= bf2f(p16[(unsigned)r >> BSHIFT]);
    atomicAdd(&acc[(unsigned)r & (BNODES - 1)], v);
  }
  __syncthreads();

  float* o = out + (size_t)part * N_NODES;
  int base = b * BNODES;
  if (base + BNODES <= N_NODES) {        // full bucket: float4 writeout
    float4* o4 = (float4*)(o + base);
    const float4* a4 = (const float4*)acc;
#pragma unroll
    for (int j = threadIdx.x; j < BNODES / 4; j += 256) o4[j] = a4[j];
  } else {
    for (int j = threadIdx.x; base + j < N_NODES; j += 256) o[base + j] = acc[j];
  }
}

// ---------------- node-wise kernels ----------------

__global__ void k_dis_p(const float* __restrict__ x, const float* __restrict__ D,
                        float* __restrict__ A, unsigned short* __restrict__ P16,
                        int split) {
  int i = blockIdx.x * blockDim.x + threadIdx.x;
  if (i >= N_NODES) return;
  float deg = 1.0f;                       // self loop
  for (int j = 0; j < split; ++j) deg += D[(size_t)j * N_NODES + i];
  float d = rsqrtf(deg);
  A[i] = d;
  P16[i] = f2bf(d * x[i]);
}

__global__ void k_g2(const float* __restrict__ A, const float* __restrict__ x,
                     const float* __restrict__ D, unsigned short* __restrict__ P16,
                     const float* __restrict__ W1, const float* __restrict__ b1,
                     const float* __restrict__ W2, int split) {
  int i = blockIdx.x * blockDim.x + threadIdx.x;
  if (i >= N_NODES) return;
  float d = A[i];
  float sraw = 0.f;
  for (int j = 0; j < split; ++j) sraw += D[(size_t)j * N_NODES + i];
  float s1 = d * sraw + d * d * x[i];
  float g = 0.f;
#pragma unroll
  for (int j = 0; j < 4; ++j) {
    float h = fmaf(s1, W1[j], b1[j]);
    g = fmaf(fmaxf(h, 0.f), W2[j], g);
  }
  P16[i] = f2bf(d * g);
}

__global__ void k_out2(const float* __restrict__ A,
                       const unsigned short* __restrict__ P16,
                       const float* __restrict__ D, const float* __restrict__ b2,
                       const float* __restrict__ Wl, const float* __restrict__ bl,
                       float* __restrict__ y, int split) {
  int i = blockIdx.x * blockDim.x + threadIdx.x;
  if (i >= N_NODES) return;
  float d = A[i];
  float g = bf2f(P16[i]) / d;             // d in (0,1], safe
  float sraw = 0.f;
  for (int j = 0; j < split; ++j) sraw += D[(size_t)j * N_NODES + i];
  float agg2 = d * sraw + d * d * g;
  float v = fmaf(agg2 + b2[0], Wl[0], bl[0]);
  y[i] = 1.0f / (1.0f + expf(-v));
}

// ---------------- fallback (round-2 global-atomic path) ----------------

__global__ void f_deg(const int* __restrict__ col, const float* __restrict__ ew,
                      float* __restrict__ deg) {
  int i = blockIdx.x * blockDim.x + threadIdx.x;
  int stride = gridDim.x * blockDim.x;
  for (int e = i; e < N_EDGES; e += stride) atomicAdd(&deg[col[e]], ew[e]);
}
__global__ void f_dis(float* __restrict__ a) {
  int i = blockIdx.x * blockDim.x + threadIdx.x;
  if (i < N_NODES) a[i] = rsqrtf(a[i] + 1.0f);
}
__global__ void f_scatter(const int* __restrict__ row, const int* __restrict__ col,
                          const float* __restrict__ ew, const float* __restrict__ dis,
                          const float* __restrict__ src, float* __restrict__ acc) {
  int i = blockIdx.x * blockDim.x + threadIdx.x;
  int stride = gridDim.x * blockDim.x;
  for (int e = i; e < N_EDGES; e += stride) {
    int r = row[e]; int c = col[e];
    atomicAdd(&acc[c], dis[r] * ew[e] * src[r]);
  }
}
__global__ void f_g(const float* __restrict__ dis, const float* __restrict__ x,
                    float* __restrict__ s1g, const float* __restrict__ W1,
                    const float* __restrict__ b1, const float* __restrict__ W2) {
  int i = blockIdx.x * blockDim.x + threadIdx.x;
  if (i >= N_NODES) return;
  float d = dis[i];
  float s1 = d * s1g[i] + d * d * x[i];
  float g = 0.f;
#pragma unroll
  for (int j = 0; j < 4; ++j) {
    float h = fmaf(s1, W1[j], b1[j]);
    g = fmaf(fmaxf(h, 0.f), W2[j], g);
  }
  s1g[i] = g;
}
__global__ void f_out(const float* __restrict__ dis, const float* __restrict__ g,
                      float* __restrict__ s2out, const float* __restrict__ b2,
                      const float* __restrict__ Wl, const float* __restrict__ bl) {
  int i = blockIdx.x * blockDim.x + threadIdx.x;
  if (i >= N_NODES) return;
  float d = dis[i];
  float agg2 = d * s2out[i] + d * d * g[i];
  float v = fmaf(agg2 + b2[0], Wl[0], bl[0]);
  s2out[i] = 1.0f / (1.0f + expf(-v));
}

// ---------------- launch ----------------

extern "C" void kernel_launch(void* const* d_in, const int* in_sizes, int n_in,
                              void* d_out, int out_size, void* d_ws, size_t ws_size,
                              hipStream_t stream) {
  const float* x  = (const float*)d_in[0];
  const int* ei   = (const int*)d_in[1];   // int32 (harness narrows int64)
  const float* ew = (const float*)d_in[2];
  const float* W1 = (const float*)d_in[3];
  const float* b1 = (const float*)d_in[4];
  const float* W2 = (const float*)d_in[5];
  const float* b2 = (const float*)d_in[6];
  const float* Wl = (const float*)d_in[7];
  const float* bl = (const float*)d_in[8];

  const int* row = ei;
  const int* col = ei + N_EDGES;

  auto pad = [](size_t v) { return (v + 255) & ~(size_t)255; };
  const size_t REC_B   = pad((size_t)N_EDGES * 8);         // 128,000,000
  const size_t HIST_B  = pad((size_t)NHIST_PAD * 4);       // 5,107,712
  const size_t HISTT_B = pad((size_t)NBLK * 256 * 4);      // 5,334,016
  const size_t BSUM_B  = 8192;
  const size_t NODE_B  = pad((size_t)N_NODES * 4);
  const size_t P16_B   = pad((size_t)N_NODES * 2);
  const size_t BASE    = REC_B + HIST_B + HISTT_B + BSUM_B + NODE_B + P16_B;

  dim3 blk(256);
  dim3 ngrid((N_NODES + 255) / 256);
  dim3 tgrid((NBLK + 31) / 32, 8);
  dim3 tblk(32, 32);

  int split = 0;
  for (int s : {8, 4, 2, 1})
    if (ws_size >= BASE + (size_t)s * NODE_B) { split = s; break; }

  if (split) {
    char* w = (char*)d_ws;
    uint2* rec          = (uint2*)w;
    unsigned* hist      = (unsigned*)(w + REC_B);
    unsigned* histT     = (unsigned*)(w + REC_B + HIST_B);   // also histT2
    unsigned* bsum      = (unsigned*)(w + REC_B + HIST_B + HISTT_B);
    float* A            = (float*)(w + REC_B + HIST_B + HISTT_B + BSUM_B);
    unsigned short* P16 = (unsigned short*)((char*)A + NODE_B);
    float* D            = (float*)((char*)P16 + P16_B);      // split partials

    // zero the scan pad tail (rest of hist fully written by k_t1)
    hipMemsetAsync(hist + NHIST, 0, (size_t)(NHIST_PAD - NHIST) * 4, stream);

    k_count<<<NBLK, FBLK, 0, stream>>>(col, histT);
    k_t1   <<<tgrid, tblk, 0, stream>>>(histT, hist);
    k_scanA<<<NSCAN, SCAN_TPB, 0, stream>>>(hist, bsum);
    k_scanB<<<1, 1024, 0, stream>>>(bsum);
    k_scanC<<<NSCAN, SCAN_TPB, 0, stream>>>(hist, bsum);
    k_t2   <<<tgrid, tblk, 0, stream>>>(hist, histT);        // offsets, transposed
    k_fill <<<NBLK, FBLK, 0, stream>>>(row, col, ew, histT, rec);

    k_acc  <<<NB * split, 256, 0, stream>>>(rec, hist, nullptr, D, 0, split);
    k_dis_p<<<ngrid, blk, 0, stream>>>(x, D, A, P16, split);
    k_acc  <<<NB * split, 256, 0, stream>>>(rec, hist, P16, D, 1, split);
    k_g2   <<<ngrid, blk, 0, stream>>>(A, x, D, P16, W1, b1, W2, split);
    k_acc  <<<NB * split, 256, 0, stream>>>(rec, hist, P16, D, 1, split);
    k_out2 <<<ngrid, blk, 0, stream>>>(A, P16, D, b2, Wl, bl, (float*)d_out, split);
  } else {
    float* Aw = (float*)d_ws;
    float* Bw = Aw + N_NODES;
    float* Cw = (float*)d_out;
    hipMemsetAsync(d_ws, 0, 2ull * N_NODES * 4, stream);
    hipMemsetAsync(d_out, 0, (size_t)N_NODES * 4, stream);
    dim3 egrid(4096);
    f_deg<<<egrid, blk, 0, stream>>>(col, ew, Aw);
    f_dis<<<ngrid, blk, 0, stream>>>(Aw);
    f_scatter<<<egrid, blk, 0, stream>>>(row, col, ew, Aw, x, Bw);
    f_g<<<ngrid, blk, 0, stream>>>(Aw, x, Bw, W1, b1, W2);
    f_scatter<<<egrid, blk, 0, stream>>>(row, col, ew, Aw, Bw, Cw);
    f_out<<<ngrid, blk, 0, stream>>>(Aw, Bw, Cw, b2, Wl, bl);
  }
}

// Round 10
// 431.841 us; speedup vs baseline: 1.7707x; 1.0642x over previous
//
#include <hip/hip_runtime.h>

// GCN on 1M nodes / 16M edges, collapsed to scalar per-node features.
//
//   deg[c]  = sum_{e: col=c} ew[e] + 1 (self loop)
//   dis     = rsqrt(deg)
//   S1[c]   = dis[c] * (sum_e dis[row]*ew*x[row]) + dis[c]^2 * x[c]
//   g[c]    = sum_j relu(S1[c]*W1[j] + b1[j]) * W2[j]
//   S2[c]   = dis[c] * (sum_e dis[row]*ew*g[row]) + dis[c]^2 * g[c]
//   y[c]    = sigmoid((S2[c]+b2)*Wl + bl)
//
// R9 post-mortem: k_acc == 117us across FOUR geometries AND mode0 (no gather)
// == mode1 -> the gather was never the limit; the 8B/lane NONTEMPORAL rec
// loads are (no L2 allocation -> every pass re-misses; latency x issue-count
// bound, occupancy-insensitive). R10: uint4 loads (2 rec/load, half the
// issues) + plain cached loads (acc0 warms L2/L3 for acc1/acc2).

constexpr int N_NODES = 1000000;
constexpr int N_EDGES = 16000000;

constexpr int BSHIFT = 12;
constexpr int BNODES = 1 << BSHIFT;                    // 4096 nodes/bucket
constexpr int NB = (N_NODES + BNODES - 1) / BNODES;    // 245 buckets
constexpr int EPT = 12;                                // edges/thread in count+fill
constexpr int FBLK = 256;
constexpr int CHUNK = FBLK * EPT;                      // 3072 edges/block
constexpr int NBLK = (N_EDGES + CHUNK - 1) / CHUNK;    // 5209
constexpr int NHIST = NB * NBLK;                       // 1,276,205
constexpr int SCAN_TPB = 256;
constexpr int SCAN_EPB = 1024;
constexpr int NSCAN = (NHIST + SCAN_EPB - 1) / SCAN_EPB;  // 1247
constexpr int NHIST_PAD = NSCAN * SCAN_EPB;            // 1,276,928

__device__ inline unsigned short f2bf(float f) {   // fp32 -> bf16 RNE
  unsigned u = __float_as_uint(f);
  return (unsigned short)((u + 0x7FFFu + ((u >> 16) & 1u)) >> 16);
}
__device__ inline float bf2f(unsigned short h) {
  return __uint_as_float((unsigned)h << 16);
}

// ---------------- build: count / transpose / scan / transpose / fill --------

// histT layout [NBLK][256]: block writes its own contiguous row (coalesced).
__global__ __launch_bounds__(FBLK) void k_count(const int* __restrict__ col,
                                                unsigned* __restrict__ histT) {
  __shared__ unsigned cnt[256];
  int t = threadIdx.x;
  cnt[t] = 0;
  __syncthreads();
  int e0 = blockIdx.x * CHUNK;
  if (e0 + CHUNK <= N_EDGES) {          // fast path: all loads unguarded
    int c[EPT];
#pragma unroll
    for (int k = 0; k < EPT; ++k) c[k] = col[e0 + k * FBLK + t];
#pragma unroll
    for (int k = 0; k < EPT; ++k) atomicAdd(&cnt[c[k] >> BSHIFT], 1u);
  } else {
#pragma unroll
    for (int k = 0; k < EPT; ++k) {
      int e = e0 + k * FBLK + t;
      if (e < N_EDGES) atomicAdd(&cnt[col[e] >> BSHIFT], 1u);
    }
  }
  __syncthreads();
  histT[(size_t)blockIdx.x * 256 + t] = cnt[t];
}

// histT[NBLK][256] -> hist[b*NBLK + blk] (bucket-major flat, for linear scan)
__global__ __launch_bounds__(1024) void k_t1(const unsigned* __restrict__ in,
                                             unsigned* __restrict__ out) {
  __shared__ unsigned tile[32][33];
  int bx = blockIdx.x * 32;   // blk base
  int by = blockIdx.y * 32;   // b base
  int tx = threadIdx.x, ty = threadIdx.y;
  int rblk = bx + ty;
  if (rblk < NBLK) tile[ty][tx] = in[(size_t)rblk * 256 + by + tx];
  __syncthreads();
  int wb = by + ty, wblk = bx + tx;
  if (wb < NB && wblk < NBLK) out[(size_t)wb * NBLK + wblk] = tile[tx][ty];
}

// hist offsets (bucket-major) -> histT2[blk*256 + b] (fill reads coalesced)
__global__ __launch_bounds__(1024) void k_t2(const unsigned* __restrict__ in,
                                             unsigned* __restrict__ out) {
  __shared__ unsigned tile[32][33];
  int bx = blockIdx.x * 32;   // blk base
  int by = blockIdx.y * 32;   // b base
  int tx = threadIdx.x, ty = threadIdx.y;
  int rb = by + ty, rblk = bx + tx;
  if (rb < NB && rblk < NBLK) tile[ty][tx] = in[(size_t)rb * NBLK + rblk];
  __syncthreads();
  int wblk = bx + ty, wb = by + tx;
  if (wblk < NBLK && wb < NB) out[(size_t)wblk * 256 + wb] = tile[tx][ty];
}

__global__ __launch_bounds__(SCAN_TPB) void k_scanA(unsigned* __restrict__ h,
                                                    unsigned* __restrict__ bsum) {
  __shared__ unsigned sc[SCAN_TPB];
  int t = threadIdx.x;
  size_t base = (size_t)blockIdx.x * SCAN_EPB + (size_t)t * 4;
  uint4 v = *(const uint4*)(h + base);
  unsigned s = v.x + v.y + v.z + v.w;
  sc[t] = s;
  __syncthreads();
  for (int d = 1; d < SCAN_TPB; d <<= 1) {
    unsigned u = (t >= d) ? sc[t - d] : 0;
    __syncthreads();
    sc[t] += u;
    __syncthreads();
  }
  unsigned ex = sc[t] - s;
  uint4 o;
  o.x = ex; o.y = ex + v.x; o.z = ex + v.x + v.y; o.w = ex + v.x + v.y + v.z;
  *(uint4*)(h + base) = o;
  if (t == SCAN_TPB - 1) bsum[blockIdx.x] = sc[t];
}

__global__ __launch_bounds__(1024) void k_scanB(unsigned* __restrict__ bsum) {
  __shared__ unsigned sc[1024];
  int t = threadIdx.x;
  unsigned a0 = (2 * t < NSCAN) ? bsum[2 * t] : 0;
  unsigned a1 = (2 * t + 1 < NSCAN) ? bsum[2 * t + 1] : 0;
  unsigned s = a0 + a1;
  sc[t] = s;
  __syncthreads();
  for (int d = 1; d < 1024; d <<= 1) {
    unsigned u = (t >= d) ? sc[t - d] : 0;
    __syncthreads();
    sc[t] += u;
    __syncthreads();
  }
  unsigned ex = sc[t] - s;
  if (2 * t < NSCAN) bsum[2 * t] = ex;
  if (2 * t + 1 < NSCAN) bsum[2 * t + 1] = ex + a0;
}

__global__ __launch_bounds__(SCAN_TPB) void k_scanC(unsigned* __restrict__ h,
                                                    const unsigned* __restrict__ bsum) {
  unsigned add = bsum[blockIdx.x];
  size_t base = (size_t)blockIdx.x * SCAN_EPB + (size_t)threadIdx.x * 4;
  uint4 v = *(uint4*)(h + base);
  v.x += add; v.y += add; v.z += add; v.w += add;
  *(uint4*)(h + base) = v;
}

// Register-stash + LDS-reorder fill. Wave-shuffle scan (5 barriers), plain
// coalesced stores (nt stores cost +45us, R5/R6), 4x unrolled writeout.
// record = (row<<12 | col&0xFFF, bits(ew)); row < 2^20 fits.
__global__ __launch_bounds__(FBLK) void k_fill(const int* __restrict__ row,
                                               const int* __restrict__ col,
                                               const float* __restrict__ ew,
                                               const unsigned* __restrict__ histT2,
                                               uint2* __restrict__ rec) {
  __shared__ unsigned lhist[256];
  __shared__ unsigned lb[256];
  __shared__ unsigned tail[256];
  __shared__ unsigned gbase[NB];
  __shared__ unsigned wsum[4];
  __shared__ uint2 stage[CHUNK];
  __shared__ unsigned char sbkt[CHUNK];

  int t = threadIdx.x;
  int blk = blockIdx.x;
  lhist[t] = 0;
  if (t < NB) gbase[t] = histT2[(size_t)blk * 256 + t];  // coalesced row read
  __syncthreads();                                        // B1

  int e0 = blk * CHUNK;
  unsigned pk[EPT], wv[EPT];
  int bk[EPT];
  if (e0 + CHUNK <= N_EDGES) {          // fast path (5208 of 5209 blocks)
#pragma unroll
    for (int k = 0; k < EPT; ++k) {
      int e = e0 + k * FBLK + t;
      int c = col[e];
      pk[k] = ((unsigned)row[e] << BSHIFT) | (unsigned)(c & (BNODES - 1));
      wv[k] = __float_as_uint(ew[e]);
      bk[k] = c >> BSHIFT;
    }
#pragma unroll
    for (int k = 0; k < EPT; ++k) atomicAdd(&lhist[bk[k]], 1u);
  } else {
#pragma unroll
    for (int k = 0; k < EPT; ++k) {
      int e = e0 + k * FBLK + t;
      bk[k] = -1;
      if (e < N_EDGES) {
        int c = col[e];
        pk[k] = ((unsigned)row[e] << BSHIFT) | (unsigned)(c & (BNODES - 1));
        wv[k] = __float_as_uint(ew[e]);
        bk[k] = c >> BSHIFT;
        atomicAdd(&lhist[bk[k]], 1u);
      }
    }
  }
  __syncthreads();                                        // B2

  // exclusive prefix over 256 bucket counts: wave scan + 4-entry fixup
  unsigned own = lhist[t];
  unsigned v = own;
#pragma unroll
  for (int d = 1; d < 64; d <<= 1) {
    unsigned u = __shfl_up(v, d, 64);
    if ((t & 63) >= d) v += u;
  }
  if ((t & 63) == 63) wsum[t >> 6] = v;
  __syncthreads();                                        // B3
  unsigned wbase = 0;
#pragma unroll
  for (int w = 0; w < 4; ++w)
    if (w < (t >> 6)) wbase += wsum[w];
  unsigned total = wsum[0] + wsum[1] + wsum[2] + wsum[3];
  unsigned ex = wbase + v - own;
  lb[t] = ex;
  tail[t] = ex;
  __syncthreads();                                        // B4

  if (e0 + CHUNK <= N_EDGES) {
#pragma unroll
    for (int k = 0; k < EPT; ++k) {
      unsigned s = atomicAdd(&tail[bk[k]], 1u);
      stage[s] = make_uint2(pk[k], wv[k]);
      sbkt[s] = (unsigned char)bk[k];
    }
  } else {
#pragma unroll
    for (int k = 0; k < EPT; ++k) {
      if (bk[k] >= 0) {
        unsigned s = atomicAdd(&tail[bk[k]], 1u);
        stage[s] = make_uint2(pk[k], wv[k]);
        sbkt[s] = (unsigned char)bk[k];
      }
    }
  }
  __syncthreads();                                        // B5

  // staged order is bucket-sorted: consecutive s -> consecutive global dest.
  // 4x unroll: independent LDS-read -> store chains in flight.
  unsigned s = t;
  for (; s + 3u * FBLK < total; s += 4u * FBLK) {
#pragma unroll
    for (int u = 0; u < 4; ++u) {
      unsigned si = s + u * FBLK;
      unsigned b = sbkt[si];
      rec[gbase[b] + (si - lb[b])] = stage[si];
    }
  }
  for (; s < total; s += FBLK) {
    unsigned b = sbkt[s];
    rec[gbase[b] + (s - lb[b])] = stage[s];
  }
}

// ---------------- accumulate: one (bucket,part) per block ----------------
// mode 0: val = ew (weighted degree). mode 1: val = ew * bf16 p16[row].
// uint4 loads (2 records / 16B issue), PLAIN cached loads (L2/L3 reuse
// across the three passes), 8 loads = 16 records in flight per thread.
__global__ __launch_bounds__(256) void k_acc(const uint2* __restrict__ rec,
                                             const unsigned* __restrict__ hist,
                                             const unsigned short* __restrict__ p16,
                                             float* __restrict__ out,
                                             int mode, int split) {
  __shared__ float acc[BNODES];
  {
    float4* a4 = (float4*)acc;
#pragma unroll
    for (int i = threadIdx.x; i < BNODES / 4; i += 256)
      a4[i] = make_float4(0.f, 0.f, 0.f, 0.f);
  }
  __syncthreads();
  int b = blockIdx.x / split;
  int part = blockIdx.x - b * split;
  unsigned bs = hist[(size_t)b * NBLK];
  unsigned be = (b + 1 < NB) ? hist[(size_t)(b + 1) * NBLK] : (unsigned)N_EDGES;
  unsigned len = be - bs;
  unsigned s = bs + (unsigned)(((unsigned long long)len * part) / split);
  unsigned e = bs + (unsigned)(((unsigned long long)len * (part + 1)) / split);
  unsigned t = threadIdx.x;

  if ((s & 1u) && s < e) {               // odd start: one scalar record
    if (t == 0) {
      uint2 r = rec[s];
      float v = __uint_as_float(r.y);
      if (mode) v *= bf2f(p16[r.x >> BSHIFT]);
      atomicAdd(&acc[r.x & (BNODES - 1)], v);
    }
    s++;
  }
  unsigned n = (e > s) ? (e - s) : 0u;
  unsigned npair = n >> 1;               // # of uint4 (2-record) loads
  const uint4* rec4 = (const uint4*)(rec + s);   // 16B-aligned (s even)

  unsigned ip = t;
  for (; ip + 7u * 256u < npair; ip += 8u * 256u) {   // 16 records in flight
    uint4 q[8];
#pragma unroll
    for (int j = 0; j < 8; ++j) q[j] = rec4[ip + (unsigned)j * 256u];
    float v0[8], v1[8];
#pragma unroll
    for (int j = 0; j < 8; ++j) {
      v0[j] = __uint_as_float(q[j].y);
      v1[j] = __uint_as_float(q[j].w);
      if (mode) {
        v0[j] *= bf2f(p16[q[j].x >> BSHIFT]);
        v1[j] *= bf2f(p16[q[j].z >> BSHIFT]);
      }
    }
#pragma unroll
    for (int j = 0; j < 8; ++j) {
      atomicAdd(&acc[q[j].x & (BNODES - 1)], v0[j]);
      atomicAdd(&acc[q[j].z & (BNODES - 1)], v1[j]);
    }
  }
  for (; ip < npair; ip += 256u) {
    uint4 q = rec4[ip];
    float v0 = __uint_as_float(q.y), v1 = __uint_as_float(q.w);
    if (mode) {
      v0 *= bf2f(p16[q.x >> BSHIFT]);
      v1 *= bf2f(p16[q.z >> BSHIFT]);
    }
    atomicAdd(&acc[q.x & (BNODES - 1)], v0);
    atomicAdd(&acc[q.z & (BNODES - 1)], v1);
  }
  if ((n & 1u) && t == 0) {              // odd tail: one scalar record
    uint2 r = rec[s + n - 1u];
    float v = __uint_as_float(r.y);
    if (mode) v *= bf2f(p16[r.x >> BSHIFT]);
    atomicAdd(&acc[r.x & (BNODES - 1)], v);
  }
  __syncthreads();

  float* o = out + (size_t)part * N_NODES;
  int base = b * BNODES;
  if (base + BNODES <= N_NODES) {        // full bucket: float4 writeout
    float4* o4 = (float4*)(o + base);
    const float4* a4 = (const float4*)acc;
#pragma unroll
    for (int j = threadIdx.x; j < BNODES / 4; j += 256) o4[j] = a4[j];
  } else {
    for (int j = threadIdx.x; base + j < N_NODES; j += 256) o[base + j] = acc[j];
  }
}

// ---------------- node-wise kernels ----------------

__global__ void k_dis_p(const float* __restrict__ x, const float* __restrict__ D,
                        float* __restrict__ A, unsigned short* __restrict__ P16,
                        int split) {
  int i = blockIdx.x * blockDim.x + threadIdx.x;
  if (i >= N_NODES) return;
  float deg = 1.0f;                       // self loop
  for (int j = 0; j < split; ++j) deg += D[(size_t)j * N_NODES + i];
  float d = rsqrtf(deg);
  A[i] = d;
  P16[i] = f2bf(d * x[i]);
}

__global__ void k_g2(const float* __restrict__ A, const float* __restrict__ x,
                     const float* __restrict__ D, unsigned short* __restrict__ P16,
                     const float* __restrict__ W1, const float* __restrict__ b1,
                     const float* __restrict__ W2, int split) {
  int i = blockIdx.x * blockDim.x + threadIdx.x;
  if (i >= N_NODES) return;
  float d = A[i];
  float sraw = 0.f;
  for (int j = 0; j < split; ++j) sraw += D[(size_t)j * N_NODES + i];
  float s1 = d * sraw + d * d * x[i];
  float g = 0.f;
#pragma unroll
  for (int j = 0; j < 4; ++j) {
    float h = fmaf(s1, W1[j], b1[j]);
    g = fmaf(fmaxf(h, 0.f), W2[j], g);
  }
  P16[i] = f2bf(d * g);
}

__global__ void k_out2(const float* __restrict__ A,
                       const unsigned short* __restrict__ P16,
                       const float* __restrict__ D, const float* __restrict__ b2,
                       const float* __restrict__ Wl, const float* __restrict__ bl,
                       float* __restrict__ y, int split) {
  int i = blockIdx.x * blockDim.x + threadIdx.x;
  if (i >= N_NODES) return;
  float d = A[i];
  float g = bf2f(P16[i]) / d;             // d in (0,1], safe
  float sraw = 0.f;
  for (int j = 0; j < split; ++j) sraw += D[(size_t)j * N_NODES + i];
  float agg2 = d * sraw + d * d * g;
  float v = fmaf(agg2 + b2[0], Wl[0], bl[0]);
  y[i] = 1.0f / (1.0f + expf(-v));
}

// ---------------- fallback (round-2 global-atomic path) ----------------

__global__ void f_deg(const int* __restrict__ col, const float* __restrict__ ew,
                      float* __restrict__ deg) {
  int i = blockIdx.x * blockDim.x + threadIdx.x;
  int stride = gridDim.x * blockDim.x;
  for (int e = i; e < N_EDGES; e += stride) atomicAdd(&deg[col[e]], ew[e]);
}
__global__ void f_dis(float* __restrict__ a) {
  int i = blockIdx.x * blockDim.x + threadIdx.x;
  if (i < N_NODES) a[i] = rsqrtf(a[i] + 1.0f);
}
__global__ void f_scatter(const int* __restrict__ row, const int* __restrict__ col,
                          const float* __restrict__ ew, const float* __restrict__ dis,
                          const float* __restrict__ src, float* __restrict__ acc) {
  int i = blockIdx.x * blockDim.x + threadIdx.x;
  int stride = gridDim.x * blockDim.x;
  for (int e = i; e < N_EDGES; e += stride) {
    int r = row[e]; int c = col[e];
    atomicAdd(&acc[c], dis[r] * ew[e] * src[r]);
  }
}
__global__ void f_g(const float* __restrict__ dis, const float* __restrict__ x,
                    float* __restrict__ s1g, const float* __restrict__ W1,
                    const float* __restrict__ b1, const float* __restrict__ W2) {
  int i = blockIdx.x * blockDim.x + threadIdx.x;
  if (i >= N_NODES) return;
  float d = dis[i];
  float s1 = d * s1g[i] + d * d * x[i];
  float g = 0.f;
#pragma unroll
  for (int j = 0; j < 4; ++j) {
    float h = fmaf(s1, W1[j], b1[j]);
    g = fmaf(fmaxf(h, 0.f), W2[j], g);
  }
  s1g[i] = g;
}
__global__ void f_out(const float* __restrict__ dis, const float* __restrict__ g,
                      float* __restrict__ s2out, const float* __restrict__ b2,
                      const float* __restrict__ Wl, const float* __restrict__ bl) {
  int i = blockIdx.x * blockDim.x + threadIdx.x;
  if (i >= N_NODES) return;
  float d = dis[i];
  float agg2 = d * s2out[i] + d * d * g[i];
  float v = fmaf(agg2 + b2[0], Wl[0], bl[0]);
  s2out[i] = 1.0f / (1.0f + expf(-v));
}

// ---------------- launch ----------------

extern "C" void kernel_launch(void* const* d_in, const int* in_sizes, int n_in,
                              void* d_out, int out_size, void* d_ws, size_t ws_size,
                              hipStream_t stream) {
  const float* x  = (const float*)d_in[0];
  const int* ei   = (const int*)d_in[1];   // int32 (harness narrows int64)
  const float* ew = (const float*)d_in[2];
  const float* W1 = (const float*)d_in[3];
  const float* b1 = (const float*)d_in[4];
  const float* W2 = (const float*)d_in[5];
  const float* b2 = (const float*)d_in[6];
  const float* Wl = (const float*)d_in[7];
  const float* bl = (const float*)d_in[8];

  const int* row = ei;
  const int* col = ei + N_EDGES;

  auto pad = [](size_t v) { return (v + 255) & ~(size_t)255; };
  const size_t REC_B   = pad((size_t)N_EDGES * 8);         // 128,000,000
  const size_t HIST_B  = pad((size_t)NHIST_PAD * 4);       // 5,107,712
  const size_t HISTT_B = pad((size_t)NBLK * 256 * 4);      // 5,334,016
  const size_t BSUM_B  = 8192;
  const size_t NODE_B  = pad((size_t)N_NODES * 4);
  const size_t P16_B   = pad((size_t)N_NODES * 2);
  const size_t BASE    = REC_B + HIST_B + HISTT_B + BSUM_B + NODE_B + P16_B;

  dim3 blk(256);
  dim3 ngrid((N_NODES + 255) / 256);
  dim3 tgrid((NBLK + 31) / 32, 8);
  dim3 tblk(32, 32);

  int split = 0;
  for (int s : {8, 4, 2, 1})
    if (ws_size >= BASE + (size_t)s * NODE_B) { split = s; break; }

  if (split) {
    char* w = (char*)d_ws;
    uint2* rec          = (uint2*)w;
    unsigned* hist      = (unsigned*)(w + REC_B);
    unsigned* histT     = (unsigned*)(w + REC_B + HIST_B);   // also histT2
    unsigned* bsum      = (unsigned*)(w + REC_B + HIST_B + HISTT_B);
    float* A            = (float*)(w + REC_B + HIST_B + HISTT_B + BSUM_B);
    unsigned short* P16 = (unsigned short*)((char*)A + NODE_B);
    float* D            = (float*)((char*)P16 + P16_B);      // split partials

    // zero the scan pad tail (rest of hist fully written by k_t1)
    hipMemsetAsync(hist + NHIST, 0, (size_t)(NHIST_PAD - NHIST) * 4, stream);

    k_count<<<NBLK, FBLK, 0, stream>>>(col, histT);
    k_t1   <<<tgrid, tblk, 0, stream>>>(histT, hist);
    k_scanA<<<NSCAN, SCAN_TPB, 0, stream>>>(hist, bsum);
    k_scanB<<<1, 1024, 0, stream>>>(bsum);
    k_scanC<<<NSCAN, SCAN_TPB, 0, stream>>>(hist, bsum);
    k_t2   <<<tgrid, tblk, 0, stream>>>(hist, histT);        // offsets, transposed
    k_fill <<<NBLK, FBLK, 0, stream>>>(row, col, ew, histT, rec);

    k_acc  <<<NB * split, 256, 0, stream>>>(rec, hist, nullptr, D, 0, split);
    k_dis_p<<<ngrid, blk, 0, stream>>>(x, D, A, P16, split);
    k_acc  <<<NB * split, 256, 0, stream>>>(rec, hist, P16, D, 1, split);
    k_g2   <<<ngrid, blk, 0, stream>>>(A, x, D, P16, W1, b1, W2, split);
    k_acc  <<<NB * split, 256, 0, stream>>>(rec, hist, P16, D, 1, split);
    k_out2 <<<ngrid, blk, 0, stream>>>(A, P16, D, b2, Wl, bl, (float*)d_out, split);
  } else {
    float* Aw = (float*)d_ws;
    float* Bw = Aw + N_NODES;
    float* Cw = (float*)d_out;
    hipMemsetAsync(d_ws, 0, 2ull * N_NODES * 4, stream);
    hipMemsetAsync(d_out, 0, (size_t)N_NODES * 4, stream);
    dim3 egrid(4096);
    f_deg<<<egrid, blk, 0, stream>>>(col, ew, Aw);
    f_dis<<<ngrid, blk, 0, stream>>>(Aw);
    f_scatter<<<egrid, blk, 0, stream>>>(row, col, ew, Aw, x, Bw);
    f_g<<<ngrid, blk, 0, stream>>>(Aw, x, Bw, W1, b1, W2);
    f_scatter<<<egrid, blk, 0, stream>>>(row, col, ew, Aw, Bw, Cw);
    f_out<<<ngrid, blk, 0, stream>>>(Aw, Bw, Cw, b2, Wl, bl);
  }
}

// Round 11
// 411.246 us; speedup vs baseline: 1.8594x; 1.0501x over previous
//
#include <hip/hip_runtime.h>

// GCN on 1M nodes / 16M edges, collapsed to scalar per-node features.
//
//   deg[c]  = sum_{e: col=c} ew[e] + 1 (self loop)
//   dis     = rsqrt(deg)
//   S1[c]   = dis[c] * (sum_e dis[row]*ew*x[row]) + dis[c]^2 * x[c]
//   g[c]    = sum_j relu(S1[c]*W1[j] + b1[j]) * W2[j]
//   S2[c]   = dis[c] * (sum_e dis[row]*ew*g[row]) + dis[c]^2 * g[c]
//   y[c]    = sigmoid((S2[c]+b2)*Wl + bl)
//
// R10 post-mortem: k_acc VGPR_Count=16 -> compiler software-pipelined the
// 8x uint4 unroll down to ~2-3 outstanding loads (8 in flight need >=32
// VGPRs). Source-level ILP wasn't reaching the ISA. R11: sched_barrier(0)
// between load-phase and use-phase (k_acc rec loads, p16 gathers, k_fill
// staging loads) to force the batch issue; split 8->4 (acc is occupancy-
// insensitive, split=8's extra partial-array traffic is waste).

constexpr int N_NODES = 1000000;
constexpr int N_EDGES = 16000000;

constexpr int BSHIFT = 12;
constexpr int BNODES = 1 << BSHIFT;                    // 4096 nodes/bucket
constexpr int NB = (N_NODES + BNODES - 1) / BNODES;    // 245 buckets
constexpr int EPT = 12;                                // edges/thread in count+fill
constexpr int FBLK = 256;
constexpr int CHUNK = FBLK * EPT;                      // 3072 edges/block
constexpr int NBLK = (N_EDGES + CHUNK - 1) / CHUNK;    // 5209
constexpr int NHIST = NB * NBLK;                       // 1,276,205
constexpr int SCAN_TPB = 256;
constexpr int SCAN_EPB = 1024;
constexpr int NSCAN = (NHIST + SCAN_EPB - 1) / SCAN_EPB;  // 1247
constexpr int NHIST_PAD = NSCAN * SCAN_EPB;            // 1,276,928

__device__ inline unsigned short f2bf(float f) {   // fp32 -> bf16 RNE
  unsigned u = __float_as_uint(f);
  return (unsigned short)((u + 0x7FFFu + ((u >> 16) & 1u)) >> 16);
}
__device__ inline float bf2f(unsigned short h) {
  return __uint_as_float((unsigned)h << 16);
}

// ---------------- build: count / transpose / scan / transpose / fill --------

// histT layout [NBLK][256]: block writes its own contiguous row (coalesced).
__global__ __launch_bounds__(FBLK) void k_count(const int* __restrict__ col,
                                                unsigned* __restrict__ histT) {
  __shared__ unsigned cnt[256];
  int t = threadIdx.x;
  cnt[t] = 0;
  __syncthreads();
  int e0 = blockIdx.x * CHUNK;
  if (e0 + CHUNK <= N_EDGES) {          // fast path: all loads unguarded
    int c[EPT];
#pragma unroll
    for (int k = 0; k < EPT; ++k) c[k] = col[e0 + k * FBLK + t];
    __builtin_amdgcn_sched_barrier(0);  // keep the load batch issued together
#pragma unroll
    for (int k = 0; k < EPT; ++k) atomicAdd(&cnt[c[k] >> BSHIFT], 1u);
  } else {
#pragma unroll
    for (int k = 0; k < EPT; ++k) {
      int e = e0 + k * FBLK + t;
      if (e < N_EDGES) atomicAdd(&cnt[col[e] >> BSHIFT], 1u);
    }
  }
  __syncthreads();
  histT[(size_t)blockIdx.x * 256 + t] = cnt[t];
}

// histT[NBLK][256] -> hist[b*NBLK + blk] (bucket-major flat, for linear scan)
__global__ __launch_bounds__(1024) void k_t1(const unsigned* __restrict__ in,
                                             unsigned* __restrict__ out) {
  __shared__ unsigned tile[32][33];
  int bx = blockIdx.x * 32;   // blk base
  int by = blockIdx.y * 32;   // b base
  int tx = threadIdx.x, ty = threadIdx.y;
  int rblk = bx + ty;
  if (rblk < NBLK) tile[ty][tx] = in[(size_t)rblk * 256 + by + tx];
  __syncthreads();
  int wb = by + ty, wblk = bx + tx;
  if (wb < NB && wblk < NBLK) out[(size_t)wb * NBLK + wblk] = tile[tx][ty];
}

// hist offsets (bucket-major) -> histT2[blk*256 + b] (fill reads coalesced)
__global__ __launch_bounds__(1024) void k_t2(const unsigned* __restrict__ in,
                                             unsigned* __restrict__ out) {
  __shared__ unsigned tile[32][33];
  int bx = blockIdx.x * 32;   // blk base
  int by = blockIdx.y * 32;   // b base
  int tx = threadIdx.x, ty = threadIdx.y;
  int rb = by + ty, rblk = bx + tx;
  if (rb < NB && rblk < NBLK) tile[ty][tx] = in[(size_t)rb * NBLK + rblk];
  __syncthreads();
  int wblk = bx + ty, wb = by + tx;
  if (wblk < NBLK && wb < NB) out[(size_t)wblk * 256 + wb] = tile[tx][ty];
}

__global__ __launch_bounds__(SCAN_TPB) void k_scanA(unsigned* __restrict__ h,
                                                    unsigned* __restrict__ bsum) {
  __shared__ unsigned sc[SCAN_TPB];
  int t = threadIdx.x;
  size_t base = (size_t)blockIdx.x * SCAN_EPB + (size_t)t * 4;
  uint4 v = *(const uint4*)(h + base);
  unsigned s = v.x + v.y + v.z + v.w;
  sc[t] = s;
  __syncthreads();
  for (int d = 1; d < SCAN_TPB; d <<= 1) {
    unsigned u = (t >= d) ? sc[t - d] : 0;
    __syncthreads();
    sc[t] += u;
    __syncthreads();
  }
  unsigned ex = sc[t] - s;
  uint4 o;
  o.x = ex; o.y = ex + v.x; o.z = ex + v.x + v.y; o.w = ex + v.x + v.y + v.z;
  *(uint4*)(h + base) = o;
  if (t == SCAN_TPB - 1) bsum[blockIdx.x] = sc[t];
}

__global__ __launch_bounds__(1024) void k_scanB(unsigned* __restrict__ bsum) {
  __shared__ unsigned sc[1024];
  int t = threadIdx.x;
  unsigned a0 = (2 * t < NSCAN) ? bsum[2 * t] : 0;
  unsigned a1 = (2 * t + 1 < NSCAN) ? bsum[2 * t + 1] : 0;
  unsigned s = a0 + a1;
  sc[t] = s;
  __syncthreads();
  for (int d = 1; d < 1024; d <<= 1) {
    unsigned u = (t >= d) ? sc[t - d] : 0;
    __syncthreads();
    sc[t] += u;
    __syncthreads();
  }
  unsigned ex = sc[t] - s;
  if (2 * t < NSCAN) bsum[2 * t] = ex;
  if (2 * t + 1 < NSCAN) bsum[2 * t + 1] = ex + a0;
}

__global__ __launch_bounds__(SCAN_TPB) void k_scanC(unsigned* __restrict__ h,
                                                    const unsigned* __restrict__ bsum) {
  unsigned add = bsum[blockIdx.x];
  size_t base = (size_t)blockIdx.x * SCAN_EPB + (size_t)threadIdx.x * 4;
  uint4 v = *(uint4*)(h + base);
  v.x += add; v.y += add; v.z += add; v.w += add;
  *(uint4*)(h + base) = v;
}

// Register-stash + LDS-reorder fill. Wave-shuffle scan (5 barriers), plain
// coalesced stores (nt stores cost +45us, R5/R6), 4x unrolled writeout.
// record = (row<<12 | col&0xFFF, bits(ew)); row < 2^20 fits.
__global__ __launch_bounds__(FBLK) void k_fill(const int* __restrict__ row,
                                               const int* __restrict__ col,
                                               const float* __restrict__ ew,
                                               const unsigned* __restrict__ histT2,
                                               uint2* __restrict__ rec) {
  __shared__ unsigned lhist[256];
  __shared__ unsigned lb[256];
  __shared__ unsigned tail[256];
  __shared__ unsigned gbase[NB];
  __shared__ unsigned wsum[4];
  __shared__ uint2 stage[CHUNK];
  __shared__ unsigned char sbkt[CHUNK];

  int t = threadIdx.x;
  int blk = blockIdx.x;
  lhist[t] = 0;
  if (t < NB) gbase[t] = histT2[(size_t)blk * 256 + t];  // coalesced row read
  __syncthreads();                                        // B1

  int e0 = blk * CHUNK;
  unsigned pk[EPT], wv[EPT];
  int bk[EPT];
  if (e0 + CHUNK <= N_EDGES) {          // fast path (5208 of 5209 blocks)
    int cv[EPT], rv[EPT];
#pragma unroll
    for (int k = 0; k < EPT; ++k) {
      int e = e0 + k * FBLK + t;
      cv[k] = col[e];
      rv[k] = row[e];
      wv[k] = __float_as_uint(ew[e]);
    }
    __builtin_amdgcn_sched_barrier(0);  // 36 loads in flight before any use
#pragma unroll
    for (int k = 0; k < EPT; ++k) {
      pk[k] = ((unsigned)rv[k] << BSHIFT) | (unsigned)(cv[k] & (BNODES - 1));
      bk[k] = cv[k] >> BSHIFT;
    }
#pragma unroll
    for (int k = 0; k < EPT; ++k) atomicAdd(&lhist[bk[k]], 1u);
  } else {
#pragma unroll
    for (int k = 0; k < EPT; ++k) {
      int e = e0 + k * FBLK + t;
      bk[k] = -1;
      if (e < N_EDGES) {
        int c = col[e];
        pk[k] = ((unsigned)row[e] << BSHIFT) | (unsigned)(c & (BNODES - 1));
        wv[k] = __float_as_uint(ew[e]);
        bk[k] = c >> BSHIFT;
        atomicAdd(&lhist[bk[k]], 1u);
      }
    }
  }
  __syncthreads();                                        // B2

  // exclusive prefix over 256 bucket counts: wave scan + 4-entry fixup
  unsigned own = lhist[t];
  unsigned v = own;
#pragma unroll
  for (int d = 1; d < 64; d <<= 1) {
    unsigned u = __shfl_up(v, d, 64);
    if ((t & 63) >= d) v += u;
  }
  if ((t & 63) == 63) wsum[t >> 6] = v;
  __syncthreads();                                        // B3
  unsigned wbase = 0;
#pragma unroll
  for (int w = 0; w < 4; ++w)
    if (w < (t >> 6)) wbase += wsum[w];
  unsigned total = wsum[0] + wsum[1] + wsum[2] + wsum[3];
  unsigned ex = wbase + v - own;
  lb[t] = ex;
  tail[t] = ex;
  __syncthreads();                                        // B4

  if (e0 + CHUNK <= N_EDGES) {
#pragma unroll
    for (int k = 0; k < EPT; ++k) {
      unsigned s = atomicAdd(&tail[bk[k]], 1u);
      stage[s] = make_uint2(pk[k], wv[k]);
      sbkt[s] = (unsigned char)bk[k];
    }
  } else {
#pragma unroll
    for (int k = 0; k < EPT; ++k) {
      if (bk[k] >= 0) {
        unsigned s = atomicAdd(&tail[bk[k]], 1u);
        stage[s] = make_uint2(pk[k], wv[k]);
        sbkt[s] = (unsigned char)bk[k];
      }
    }
  }
  __syncthreads();                                        // B5

  // staged order is bucket-sorted: consecutive s -> consecutive global dest.
  // 4x unroll: independent LDS-read -> store chains in flight.
  unsigned s = t;
  for (; s + 3u * FBLK < total; s += 4u * FBLK) {
#pragma unroll
    for (int u = 0; u < 4; ++u) {
      unsigned si = s + u * FBLK;
      unsigned b = sbkt[si];
      rec[gbase[b] + (si - lb[b])] = stage[si];
    }
  }
  for (; s < total; s += FBLK) {
    unsigned b = sbkt[s];
    rec[gbase[b] + (s - lb[b])] = stage[s];
  }
}

// ---------------- accumulate: one (bucket,part) per block ----------------
// mode 0: val = ew (weighted degree). mode 1: val = ew * bf16 p16[row].
// uint4 loads (2 rec / 16B issue), cached; sched_barrier(0) after each load
// batch forces genuinely 16 records (and 16 gathers) in flight per thread.
__global__ __launch_bounds__(256) void k_acc(const uint2* __restrict__ rec,
                                             const unsigned* __restrict__ hist,
                                             const unsigned short* __restrict__ p16,
                                             float* __restrict__ out,
                                             int mode, int split) {
  __shared__ float acc[BNODES];
  {
    float4* a4 = (float4*)acc;
#pragma unroll
    for (int i = threadIdx.x; i < BNODES / 4; i += 256)
      a4[i] = make_float4(0.f, 0.f, 0.f, 0.f);
  }
  __syncthreads();
  int b = blockIdx.x / split;
  int part = blockIdx.x - b * split;
  unsigned bs = hist[(size_t)b * NBLK];
  unsigned be = (b + 1 < NB) ? hist[(size_t)(b + 1) * NBLK] : (unsigned)N_EDGES;
  unsigned len = be - bs;
  unsigned s = bs + (unsigned)(((unsigned long long)len * part) / split);
  unsigned e = bs + (unsigned)(((unsigned long long)len * (part + 1)) / split);
  unsigned t = threadIdx.x;

  if ((s & 1u) && s < e) {               // odd start: one scalar record
    if (t == 0) {
      uint2 r = rec[s];
      float v = __uint_as_float(r.y);
      if (mode) v *= bf2f(p16[r.x >> BSHIFT]);
      atomicAdd(&acc[r.x & (BNODES - 1)], v);
    }
    s++;
  }
  unsigned n = (e > s) ? (e - s) : 0u;
  unsigned npair = n >> 1;               // # of uint4 (2-record) loads
  const uint4* rec4 = (const uint4*)(rec + s);   // 16B-aligned (s even)

  unsigned ip = t;
  for (; ip + 7u * 256u < npair; ip += 8u * 256u) {   // 16 records in flight
    uint4 q[8];
#pragma unroll
    for (int j = 0; j < 8; ++j) q[j] = rec4[ip + (unsigned)j * 256u];
    __builtin_amdgcn_sched_barrier(0);   // all 8 loads issued before any use
    float v0[8], v1[8];
    if (mode) {
      unsigned short g0[8], g1[8];
#pragma unroll
      for (int j = 0; j < 8; ++j) {
        g0[j] = p16[q[j].x >> BSHIFT];
        g1[j] = p16[q[j].z >> BSHIFT];
      }
      __builtin_amdgcn_sched_barrier(0); // 16 gathers in flight before use
#pragma unroll
      for (int j = 0; j < 8; ++j) {
        v0[j] = __uint_as_float(q[j].y) * bf2f(g0[j]);
        v1[j] = __uint_as_float(q[j].w) * bf2f(g1[j]);
      }
    } else {
#pragma unroll
      for (int j = 0; j < 8; ++j) {
        v0[j] = __uint_as_float(q[j].y);
        v1[j] = __uint_as_float(q[j].w);
      }
    }
#pragma unroll
    for (int j = 0; j < 8; ++j) {
      atomicAdd(&acc[q[j].x & (BNODES - 1)], v0[j]);
      atomicAdd(&acc[q[j].z & (BNODES - 1)], v1[j]);
    }
  }
  for (; ip < npair; ip += 256u) {
    uint4 q = rec4[ip];
    float v0 = __uint_as_float(q.y), v1 = __uint_as_float(q.w);
    if (mode) {
      v0 *= bf2f(p16[q.x >> BSHIFT]);
      v1 *= bf2f(p16[q.z >> BSHIFT]);
    }
    atomicAdd(&acc[q.x & (BNODES - 1)], v0);
    atomicAdd(&acc[q.z & (BNODES - 1)], v1);
  }
  if ((n & 1u) && t == 0) {              // odd tail: one scalar record
    uint2 r = rec[s + n - 1u];
    float v = __uint_as_float(r.y);
    if (mode) v *= bf2f(p16[r.x >> BSHIFT]);
    atomicAdd(&acc[r.x & (BNODES - 1)], v);
  }
  __syncthreads();

  float* o = out + (size_t)part * N_NODES;
  int base = b * BNODES;
  if (base + BNODES <= N_NODES) {        // full bucket: float4 writeout
    float4* o4 = (float4*)(o + base);
    const float4* a4 = (const float4*)acc;
#pragma unroll
    for (int j = threadIdx.x; j < BNODES / 4; j += 256) o4[j] = a4[j];
  } else {
    for (int j = threadIdx.x; base + j < N_NODES; j += 256) o[base + j] = acc[j];
  }
}

// ---------------- node-wise kernels ----------------

__global__ void k_dis_p(const float* __restrict__ x, const float* __restrict__ D,
                        float* __restrict__ A, unsigned short* __restrict__ P16,
                        int split) {
  int i = blockIdx.x * blockDim.x + threadIdx.x;
  if (i >= N_NODES) return;
  float deg = 1.0f;                       // self loop
  for (int j = 0; j < split; ++j) deg += D[(size_t)j * N_NODES + i];
  float d = rsqrtf(deg);
  A[i] = d;
  P16[i] = f2bf(d * x[i]);
}

__global__ void k_g2(const float* __restrict__ A, const float* __restrict__ x,
                     const float* __restrict__ D, unsigned short* __restrict__ P16,
                     const float* __restrict__ W1, const float* __restrict__ b1,
                     const float* __restrict__ W2, int split) {
  int i = blockIdx.x * blockDim.x + threadIdx.x;
  if (i >= N_NODES) return;
  float d = A[i];
  float sraw = 0.f;
  for (int j = 0; j < split; ++j) sraw += D[(size_t)j * N_NODES + i];
  float s1 = d * sraw + d * d * x[i];
  float g = 0.f;
#pragma unroll
  for (int j = 0; j < 4; ++j) {
    float h = fmaf(s1, W1[j], b1[j]);
    g = fmaf(fmaxf(h, 0.f), W2[j], g);
  }
  P16[i] = f2bf(d * g);
}

__global__ void k_out2(const float* __restrict__ A,
                       const unsigned short* __restrict__ P16,
                       const float* __restrict__ D, const float* __restrict__ b2,
                       const float* __restrict__ Wl, const float* __restrict__ bl,
                       float* __restrict__ y, int split) {
  int i = blockIdx.x * blockDim.x + threadIdx.x;
  if (i >= N_NODES) return;
  float d = A[i];
  float g = bf2f(P16[i]) / d;             // d in (0,1], safe
  float sraw = 0.f;
  for (int j = 0; j < split; ++j) sraw += D[(size_t)j * N_NODES + i];
  float agg2 = d * sraw + d * d * g;
  float v = fmaf(agg2 + b2[0], Wl[0], bl[0]);
  y[i] = 1.0f / (1.0f + expf(-v));
}

// ---------------- fallback (round-2 global-atomic path) ----------------

__global__ void f_deg(const int* __restrict__ col, const float* __restrict__ ew,
                      float* __restrict__ deg) {
  int i = blockIdx.x * blockDim.x + threadIdx.x;
  int stride = gridDim.x * blockDim.x;
  for (int e = i; e < N_EDGES; e += stride) atomicAdd(&deg[col[e]], ew[e]);
}
__global__ void f_dis(float* __restrict__ a) {
  int i = blockIdx.x * blockDim.x + threadIdx.x;
  if (i < N_NODES) a[i] = rsqrtf(a[i] + 1.0f);
}
__global__ void f_scatter(const int* __restrict__ row, const int* __restrict__ col,
                          const float* __restrict__ ew, const float* __restrict__ dis,
                          const float* __restrict__ src, float* __restrict__ acc) {
  int i = blockIdx.x * blockDim.x + threadIdx.x;
  int stride = gridDim.x * blockDim.x;
  for (int e = i; e < N_EDGES; e += stride) {
    int r = row[e]; int c = col[e];
    atomicAdd(&acc[c], dis[r] * ew[e] * src[r]);
  }
}
__global__ void f_g(const float* __restrict__ dis, const float* __restrict__ x,
                    float* __restrict__ s1g, const float* __restrict__ W1,
                    const float* __restrict__ b1, const float* __restrict__ W2) {
  int i = blockIdx.x * blockDim.x + threadIdx.x;
  if (i >= N_NODES) return;
  float d = dis[i];
  float s1 = d * s1g[i] + d * d * x[i];
  float g = 0.f;
#pragma unroll
  for (int j = 0; j < 4; ++j) {
    float h = fmaf(s1, W1[j], b1[j]);
    g = fmaf(fmaxf(h, 0.f), W2[j], g);
  }
  s1g[i] = g;
}
__global__ void f_out(const float* __restrict__ dis, const float* __restrict__ g,
                      float* __restrict__ s2out, const float* __restrict__ b2,
                      const float* __restrict__ Wl, const float* __restrict__ bl) {
  int i = blockIdx.x * blockDim.x + threadIdx.x;
  if (i >= N_NODES) return;
  float d = dis[i];
  float agg2 = d * s2out[i] + d * d * g[i];
  float v = fmaf(agg2 + b2[0], Wl[0], bl[0]);
  s2out[i] = 1.0f / (1.0f + expf(-v));
}

// ---------------- launch ----------------

extern "C" void kernel_launch(void* const* d_in, const int* in_sizes, int n_in,
                              void* d_out, int out_size, void* d_ws, size_t ws_size,
                              hipStream_t stream) {
  const float* x  = (const float*)d_in[0];
  const int* ei   = (const int*)d_in[1];   // int32 (harness narrows int64)
  const float* ew = (const float*)d_in[2];
  const float* W1 = (const float*)d_in[3];
  const float* b1 = (const float*)d_in[4];
  const float* W2 = (const float*)d_in[5];
  const float* b2 = (const float*)d_in[6];
  const float* Wl = (const float*)d_in[7];
  const float* bl = (const float*)d_in[8];

  const int* row = ei;
  const int* col = ei + N_EDGES;

  auto pad = [](size_t v) { return (v + 255) & ~(size_t)255; };
  const size_t REC_B   = pad((size_t)N_EDGES * 8);         // 128,000,000
  const size_t HIST_B  = pad((size_t)NHIST_PAD * 4);       // 5,107,712
  const size_t HISTT_B = pad((size_t)NBLK * 256 * 4);      // 5,334,016
  const size_t BSUM_B  = 8192;
  const size_t NODE_B  = pad((size_t)N_NODES * 4);
  const size_t P16_B   = pad((size_t)N_NODES * 2);
  const size_t BASE    = REC_B + HIST_B + HISTT_B + BSUM_B + NODE_B + P16_B;

  dim3 blk(256);
  dim3 ngrid((N_NODES + 255) / 256);
  dim3 tgrid((NBLK + 31) / 32, 8);
  dim3 tblk(32, 32);

  int split = 0;
  for (int s : {4, 2, 1})
    if (ws_size >= BASE + (size_t)s * NODE_B) { split = s; break; }

  if (split) {
    char* w = (char*)d_ws;
    uint2* rec          = (uint2*)w;
    unsigned* hist      = (unsigned*)(w + REC_B);
    unsigned* histT     = (unsigned*)(w + REC_B + HIST_B);   // also histT2
    unsigned* bsum      = (unsigned*)(w + REC_B + HIST_B + HISTT_B);
    float* A            = (float*)(w + REC_B + HIST_B + HISTT_B + BSUM_B);
    unsigned short* P16 = (unsigned short*)((char*)A + NODE_B);
    float* D            = (float*)((char*)P16 + P16_B);      // split partials

    // zero the scan pad tail (rest of hist fully written by k_t1)
    hipMemsetAsync(hist + NHIST, 0, (size_t)(NHIST_PAD - NHIST) * 4, stream);

    k_count<<<NBLK, FBLK, 0, stream>>>(col, histT);
    k_t1   <<<tgrid, tblk, 0, stream>>>(histT, hist);
    k_scanA<<<NSCAN, SCAN_TPB, 0, stream>>>(hist, bsum);
    k_scanB<<<1, 1024, 0, stream>>>(bsum);
    k_scanC<<<NSCAN, SCAN_TPB, 0, stream>>>(hist, bsum);
    k_t2   <<<tgrid, tblk, 0, stream>>>(hist, histT);        // offsets, transposed
    k_fill <<<NBLK, FBLK, 0, stream>>>(row, col, ew, histT, rec);

    k_acc  <<<NB * split, 256, 0, stream>>>(rec, hist, nullptr, D, 0, split);
    k_dis_p<<<ngrid, blk, 0, stream>>>(x, D, A, P16, split);
    k_acc  <<<NB * split, 256, 0, stream>>>(rec, hist, P16, D, 1, split);
    k_g2   <<<ngrid, blk, 0, stream>>>(A, x, D, P16, W1, b1, W2, split);
    k_acc  <<<NB * split, 256, 0, stream>>>(rec, hist, P16, D, 1, split);
    k_out2 <<<ngrid, blk, 0, stream>>>(A, P16, D, b2, Wl, bl, (float*)d_out, split);
  } else {
    float* Aw = (float*)d_ws;
    float* Bw = Aw + N_NODES;
    float* Cw = (float*)d_out;
    hipMemsetAsync(d_ws, 0, 2ull * N_NODES * 4, stream);
    hipMemsetAsync(d_out, 0, (size_t)N_NODES * 4, stream);
    dim3 egrid(4096);
    f_deg<<<egrid, blk, 0, stream>>>(col, ew, Aw);
    f_dis<<<ngrid, blk, 0, stream>>>(Aw);
    f_scatter<<<egrid, blk, 0, stream>>>(row, col, ew, Aw, x, Bw);
    f_g<<<ngrid, blk, 0, stream>>>(Aw, x, Bw, W1, b1, W2);
    f_scatter<<<egrid, blk, 0, stream>>>(row, col, ew, Aw, Bw, Cw);
    f_out<<<ngrid, blk, 0, stream>>>(Aw, Bw, Cw, b2, Wl, bl);
  }
}